// Round 1
// baseline (1052.296 us; speedup 1.0000x reference)
//
#include <hip/hip_runtime.h>
#include <hip/hip_bf16.h>
#include <cstdint>
#include <cstddef>

#define F 768
#define TPB 256

// ---------------- CSR build (edges sorted by dst) ----------------
__global__ void khist(const int* __restrict__ ei, int E, int* __restrict__ cnt) {
  int e = blockIdx.x * blockDim.x + threadIdx.x;
  if (e < E) atomicAdd(&cnt[ei[E + e]], 1);
}

__global__ void kscan(const int* __restrict__ cnt, int* __restrict__ offs, int n) {
  // n == 2048, 256 threads, 8 elements each; exclusive scan
  __shared__ int part[TPB];
  int t = threadIdx.x;
  const int per = n / TPB; // 8
  int local[8];
  int s = 0;
  for (int j = 0; j < per; ++j) { local[j] = cnt[t * per + j]; s += local[j]; }
  part[t] = s;
  __syncthreads();
  for (int d = 1; d < TPB; d <<= 1) {
    int v = (t >= d) ? part[t - d] : 0;
    __syncthreads();
    part[t] += v;
    __syncthreads();
  }
  int run = (t == 0) ? 0 : part[t - 1];
  for (int j = 0; j < per; ++j) { offs[t * per + j] = run; run += local[j]; }
  if (t == TPB - 1) offs[n] = run;
}

__global__ void kscatter(const int* __restrict__ ei, const int* __restrict__ et, int E,
                         const int* __restrict__ offs, int* __restrict__ cur,
                         int* __restrict__ sorted) {
  int e = blockIdx.x * blockDim.x + threadIdx.x;
  if (e >= E) return;
  int dst = ei[E + e];
  int pos = offs[dst] + atomicAdd(&cur[dst], 1);
  sorted[pos] = ei[e] | (et[e] << 16);  // src < 65536, etype in {0,1,2}
}

// ---------------- per-(dst, relation) mean aggregation ----------------
__global__ void kagg(const int* __restrict__ offs, const int* __restrict__ sorted,
                     const float* __restrict__ hin, float* __restrict__ agg, int n) {
  int i = blockIdx.x, t = threadIdx.x;
  float a[3][3] = {};       // [relation][feature-chunk]
  int c0 = 0, c1 = 0, c2 = 0;
  int beg = offs[i], end = offs[i + 1];
  for (int e = beg; e < end; ++e) {
    int p = sorted[e];
    int src = p & 0xFFFF;
    int r = p >> 16;
    const float* xr = hin + (size_t)src * F;
    float v0 = xr[t], v1 = xr[t + 256], v2 = xr[t + 512];
    if (r == 0)      { a[0][0] += v0; a[0][1] += v1; a[0][2] += v2; c0++; }
    else if (r == 1) { a[1][0] += v0; a[1][1] += v1; a[1][2] += v2; c1++; }
    else             { a[2][0] += v0; a[2][1] += v1; a[2][2] += v2; c2++; }
  }
  float inv0 = 1.0f / (float)(c0 > 0 ? c0 : 1);
  float inv1 = 1.0f / (float)(c1 > 0 ? c1 : 1);
  float inv2 = 1.0f / (float)(c2 > 0 ? c2 : 1);
  float* d0 = agg + ((size_t)0 * n + i) * F;
  float* d1 = agg + ((size_t)1 * n + i) * F;
  float* d2 = agg + ((size_t)2 * n + i) * F;
  d0[t] = a[0][0] * inv0; d0[t + 256] = a[0][1] * inv0; d0[t + 512] = a[0][2] * inv0;
  d1[t] = a[1][0] * inv1; d1[t + 256] = a[1][1] * inv1; d1[t + 512] = a[1][2] * inv1;
  d2[t] = a[2][0] * inv2; d2[t + 256] = a[2][1] * inv2; d2[t + 512] = a[2][2] * inv2;
}

// ---------------- tiled fp32 GEMM ----------------
// C[m,n] = sum_k A[m,k] * (BT ? B[n,k] : B[k,n])
// EPI: 0 = store, 1 = +bias store, 3 = gate fuse, 4 = C += acc, 5 = relu(C + acc)
template <int EPI, bool BT>
__launch_bounds__(256)
__global__ void kgemm(const float* __restrict__ A, int lda,
                      const float* __restrict__ B, int ldb,
                      float* __restrict__ C, int ldc, int K,
                      const float* __restrict__ bias,
                      const float* __restrict__ aux1, int ld1,
                      const float* __restrict__ aux2, int ld2) {
  __shared__ float As[16][64];
  __shared__ float Bs[16][64];
  const int t = threadIdx.x;
  const int bm0 = blockIdx.x * 64, bn0 = blockIdx.y * 64;
  const int tr = t >> 4, tc = t & 15;   // 16x16 threads, 4x4 micro-tile
  const int lm = t >> 2, lk = (t & 3) * 4;
  float acc[4][4] = {};
  for (int k0 = 0; k0 < K; k0 += 16) {
    float4 av = *(const float4*)(A + (size_t)(bm0 + lm) * lda + k0 + lk);
    if (BT) {
      float4 bv = *(const float4*)(B + (size_t)(bn0 + lm) * ldb + k0 + lk);
      Bs[lk + 0][lm] = bv.x; Bs[lk + 1][lm] = bv.y;
      Bs[lk + 2][lm] = bv.z; Bs[lk + 3][lm] = bv.w;
    } else {
      const int kk = t >> 4, c4 = (t & 15) * 4;
      float4 bv = *(const float4*)(B + (size_t)(k0 + kk) * ldb + bn0 + c4);
      *(float4*)&Bs[kk][c4] = bv;
    }
    As[lk + 0][lm] = av.x; As[lk + 1][lm] = av.y;
    As[lk + 2][lm] = av.z; As[lk + 3][lm] = av.w;
    __syncthreads();
#pragma unroll
    for (int kk = 0; kk < 16; ++kk) {
      float4 a4 = *(const float4*)&As[kk][tr * 4];
      float4 b4 = *(const float4*)&Bs[kk][tc * 4];
      float ar[4] = {a4.x, a4.y, a4.z, a4.w};
      float br[4] = {b4.x, b4.y, b4.z, b4.w};
#pragma unroll
      for (int i = 0; i < 4; ++i)
#pragma unroll
        for (int j = 0; j < 4; ++j) acc[i][j] = fmaf(ar[i], br[j], acc[i][j]);
    }
    __syncthreads();
  }
#pragma unroll
  for (int i = 0; i < 4; ++i) {
    int row = bm0 + tr * 4 + i;
    int col0 = bn0 + tc * 4;
    float ov[4];
#pragma unroll
    for (int j = 0; j < 4; ++j) {
      int col = col0 + j;
      float v = acc[i][j];
      if (EPI == 1) {
        v += bias[col];
      } else if (EPI == 4) {
        v += C[(size_t)row * ldc + col];
      } else if (EPI == 5) {
        v += C[(size_t)row * ldc + col];
        v = fmaxf(v, 0.0f);
      } else if (EPI == 3) {
        float z = v + bias[col];
        float al = 1.0f / (1.0f + __expf(-z));
        float qiv = aux1[(size_t)row * ld1 + col];
        float hv = aux2[(size_t)row * ld2 + col];
        v = al * tanhf(qiv) + (1.0f - al) * hv;
      }
      ov[j] = v;
    }
    float4 out4 = make_float4(ov[0], ov[1], ov[2], ov[3]);
    *(float4*)(C + (size_t)row * ldc + col0) = out4;
  }
}

// ---------------- qi = sum_l sigmoid(hg + qg) * q, plus pack hqcat = [h | qi] ----
__global__ void kqi(const float* __restrict__ hg, const float* __restrict__ q,
                    const float* __restrict__ qg, const float* __restrict__ h,
                    float* __restrict__ hqcat, int npb, int L) {
  int g = blockIdx.x, t = threadIdx.x;
  int b = g / npb;
  const size_t gF = (size_t)g * F;
  float h0 = hg[gF + t], h1 = hg[gF + t + 256], h2 = hg[gF + t + 512];
  float a0 = 0.f, a1 = 0.f, a2 = 0.f;
  const float* qb = q + (size_t)b * L * F;
  const float* qgb = qg + (size_t)b * L * F;
  for (int l = 0; l < L; ++l) {
    const float* qr = qb + (size_t)l * F;
    const float* qgr = qgb + (size_t)l * F;
    float s0 = 1.0f / (1.0f + __expf(-(h0 + qgr[t])));
    float s1 = 1.0f / (1.0f + __expf(-(h1 + qgr[t + 256])));
    float s2 = 1.0f / (1.0f + __expf(-(h2 + qgr[t + 512])));
    a0 += s0 * qr[t];
    a1 += s1 * qr[t + 256];
    a2 += s2 * qr[t + 512];
  }
  float* row = hqcat + (size_t)g * (2 * F);
  row[t] = h[gF + t]; row[t + 256] = h[gF + t + 256]; row[t + 512] = h[gF + t + 512];
  row[F + t] = a0; row[F + t + 256] = a1; row[F + t + 512] = a2;
}

// ---------------- launch ----------------
extern "C" void kernel_launch(void* const* d_in, const int* in_sizes, int n_in,
                              void* d_out, int out_size, void* d_ws, size_t ws_size,
                              hipStream_t stream) {
  const float* x = (const float*)d_in[0];
  const int* ei = (const int*)d_in[1];
  const int* et = (const int*)d_in[2];
  const float* q = (const float*)d_in[3];
  const float* Wrel1 = (const float*)d_in[4];
  const float* Wroot1 = (const float*)d_in[5];
  const float* b1 = (const float*)d_in[6];
  const float* Wrel2 = (const float*)d_in[7];
  const float* Wroot2 = (const float*)d_in[8];
  const float* b2 = (const float*)d_in[9];
  const float* Wg = (const float*)d_in[10];
  const float* bg = (const float*)d_in[11];
  const float* Wq = (const float*)d_in[12];
  const float* bq = (const float*)d_in[13];

  const int BNn = in_sizes[0] / F;        // 2048
  const int E = in_sizes[1] / 2;          // 65536
  const int L = 64;
  const int Bq = in_sizes[3] / (L * F);   // 8
  const int npb = BNn / Bq;               // 256
  float* out = (float*)d_out;

  // workspace bump allocator (256B aligned)
  char* p = (char*)d_ws;
  auto alloc = [&](size_t bytes) {
    void* r = (void*)p;
    p += (bytes + 255) & ~(size_t)255;
    return r;
  };
  int* cnt = (int*)alloc((size_t)BNn * 4);
  int* cur = (int*)alloc((size_t)BNn * 4);
  int* offs = (int*)alloc((size_t)(BNn + 1) * 4);
  int* sorted = (int*)alloc((size_t)E * 4);
  float* agg = (float*)alloc((size_t)3 * BNn * F * 4);
  float* h = (float*)alloc((size_t)BNn * F * 4);
  float* hg = (float*)alloc((size_t)BNn * F * 4);
  float* qgb = (float*)alloc((size_t)Bq * L * F * 4);
  float* hqcat = (float*)alloc((size_t)BNn * 2 * F * 4);
  float* hn1 = (float*)alloc((size_t)BNn * F * 4);

  hipMemsetAsync(cnt, 0, (size_t)BNn * 4, stream);
  hipMemsetAsync(cur, 0, (size_t)BNn * 4, stream);
  khist<<<(E + 255) / 256, 256, 0, stream>>>(ei, E, cnt);
  kscan<<<1, 256, 0, stream>>>(cnt, offs, BNn);
  kscatter<<<(E + 255) / 256, 256, 0, stream>>>(ei, et, E, offs, cur, sorted);

  dim3 gBig(BNn / 64, F / 64);      // 32 x 12
  dim3 gQ(Bq * L / 64, F / 64);     // 8 x 12

  // qg depends only on (q, Wg, bg): compute once, reused by both gates
  kgemm<1, true><<<gQ, 256, 0, stream>>>(q, F, Wg + F, 2 * F, qgb, F, F, bg,
                                         nullptr, 0, nullptr, 0);

  for (int layer = 0; layer < 2; ++layer) {
    const float* hin = (layer == 0) ? x : hn1;
    const float* Wr = (layer == 0) ? Wroot1 : Wroot2;
    const float* Wl = (layer == 0) ? Wrel1 : Wrel2;
    const float* bb = (layer == 0) ? b1 : b2;
    float* gateout = (layer == 0) ? hn1 : out;

    // RGCN: h = relu(hin@Wroot + b + sum_r mean_r(hin)@Wrel_r)
    kagg<<<BNn, 256, 0, stream>>>(offs, sorted, hin, agg, BNn);
    kgemm<1, false><<<gBig, 256, 0, stream>>>(hin, F, Wr, F, h, F, F, bb,
                                              nullptr, 0, nullptr, 0);
    kgemm<4, false><<<gBig, 256, 0, stream>>>(agg, F, Wl, F, h, F, F,
                                              nullptr, nullptr, 0, nullptr, 0);
    kgemm<4, false><<<gBig, 256, 0, stream>>>(agg + (size_t)BNn * F, F, Wl + (size_t)F * F, F,
                                              h, F, F, nullptr, nullptr, 0, nullptr, 0);
    kgemm<5, false><<<gBig, 256, 0, stream>>>(agg + (size_t)2 * BNn * F, F,
                                              Wl + (size_t)2 * F * F, F, h, F, F,
                                              nullptr, nullptr, 0, nullptr, 0);

    // Gate
    kgemm<0, true><<<gBig, 256, 0, stream>>>(h, F, Wg, 2 * F, hg, F, F,
                                             nullptr, nullptr, 0, nullptr, 0);
    kqi<<<BNn, 256, 0, stream>>>(hg, q, qgb, h, hqcat, npb, L);
    kgemm<3, true><<<gBig, 256, 0, stream>>>(hqcat, 2 * F, Wq, 2 * F, gateout, F, 2 * F,
                                             bq, hqcat + F, 2 * F, h, F);
  }
}

// Round 2
// 464.526 us; speedup vs baseline: 2.2653x; 2.2653x over previous
//
#include <hip/hip_runtime.h>
#include <hip/hip_bf16.h>
#include <cstdint>
#include <cstddef>

#define F 768

typedef float f32x4 __attribute__((ext_vector_type(4)));
typedef short s16x8 __attribute__((ext_vector_type(8)));
typedef short s16x4 __attribute__((ext_vector_type(4)));

__device__ __forceinline__ float bf2f(unsigned short u) {
  union { unsigned int i; float f; } v; v.i = ((unsigned int)u) << 16; return v.f;
}
__device__ __forceinline__ unsigned short f2bf(float f) {
  union { float f; unsigned int i; } v; v.f = f;
  unsigned int r = v.i + 0x7FFF + ((v.i >> 16) & 1);  // RNE
  return (unsigned short)(r >> 16);
}

__device__ __forceinline__ void gload16(const void* g, void* l) {
  __builtin_amdgcn_global_load_lds(
      (const __attribute__((address_space(1))) void*)g,
      (__attribute__((address_space(3))) void*)l, 16, 0, 0);
}

// ---------------- CSR build (edges sorted by dst) ----------------
__global__ void khist(const int* __restrict__ ei, int E, int* __restrict__ cnt) {
  int e = blockIdx.x * blockDim.x + threadIdx.x;
  if (e < E) atomicAdd(&cnt[ei[E + e]], 1);
}

__global__ void kscan(const int* __restrict__ cnt, int* __restrict__ offs, int n) {
  __shared__ int part[256];
  int t = threadIdx.x;
  const int per = n / 256;  // 8
  int local[8];
  int s = 0;
  for (int j = 0; j < per; ++j) { local[j] = cnt[t * per + j]; s += local[j]; }
  part[t] = s;
  __syncthreads();
  for (int d = 1; d < 256; d <<= 1) {
    int v = (t >= d) ? part[t - d] : 0;
    __syncthreads();
    part[t] += v;
    __syncthreads();
  }
  int run = (t == 0) ? 0 : part[t - 1];
  for (int j = 0; j < per; ++j) { offs[t * per + j] = run; run += local[j]; }
  if (t == 255) offs[n] = run;
}

__global__ void kscatter(const int* __restrict__ ei, const int* __restrict__ et, int E,
                         const int* __restrict__ offs, int* __restrict__ cur,
                         int* __restrict__ sorted) {
  int e = blockIdx.x * blockDim.x + threadIdx.x;
  if (e >= E) return;
  int dst = ei[E + e];
  int pos = offs[dst] + atomicAdd(&cur[dst], 1);
  sorted[pos] = ei[e] | (et[e] << 16);
}

// ---------------- weight prep ----------------
// f32 contiguous [rows][cols] -> bf16 [rows][ldd]; cols = blockDim.x*4
__global__ void kcvt(const float* __restrict__ src, unsigned short* __restrict__ dst, int ldd) {
  const int r = blockIdx.x;
  const int cols = blockDim.x * 4;
  const int c = threadIdx.x * 4;
  float4 v = *(const float4*)(src + (size_t)r * cols + c);
  s16x4 o;
  o[0] = (short)f2bf(v.x); o[1] = (short)f2bf(v.y);
  o[2] = (short)f2bf(v.z); o[3] = (short)f2bf(v.w);
  *(s16x4*)(dst + (size_t)r * ldd + c) = o;
}

// transpose-convert: Wcat_l[n][part*768 + k] = Wpart[k][n], grid (12,12,8)
__global__ void ktrans(const float* __restrict__ Wr1, const float* __restrict__ Wl1,
                       const float* __restrict__ Wr2, const float* __restrict__ Wl2,
                       unsigned short* __restrict__ Wcat1, unsigned short* __restrict__ Wcat2) {
  __shared__ float tile[64][65];
  const int z = blockIdx.z, layer = z >> 2, part = z & 3;
  const float* src = (part == 0) ? (layer ? Wr2 : Wr1)
                                 : ((layer ? Wl2 : Wl1) + (size_t)(part - 1) * F * F);
  unsigned short* dst = (layer ? Wcat2 : Wcat1) + part * F;
  const int kt = blockIdx.x * 64, nt = blockIdx.y * 64;
  const int t = threadIdx.x, c = t & 63, r4 = t >> 6;
#pragma unroll
  for (int it = 0; it < 16; ++it) {
    int kk = r4 + it * 4;
    tile[kk][c] = src[(size_t)(kt + kk) * F + nt + c];
  }
  __syncthreads();
#pragma unroll
  for (int it = 0; it < 16; ++it) {
    int rr = r4 + it * 4;
    dst[(size_t)(nt + rr) * 3072 + kt + c] = f2bf(tile[c][rr]);
  }
}

// ---------------- per-(dst,relation) mean (bf16 in/out, into Acat cols 768..3071) ----
__global__ void kagg(const int* __restrict__ offs, const int* __restrict__ sorted,
                     const unsigned short* __restrict__ hin,   // Acat left, ld 3072
                     unsigned short* __restrict__ dst) {       // Acat + 768, ld 3072
  const int i = blockIdx.x, t = threadIdx.x;
  float a00 = 0, a01 = 0, a02 = 0, a10 = 0, a11 = 0, a12 = 0, a20 = 0, a21 = 0, a22 = 0;
  int c0 = 0, c1 = 0, c2 = 0;
  const int beg = offs[i], end = offs[i + 1];
  for (int e = beg; e < end; ++e) {
    int p = sorted[e];
    const unsigned short* xr = hin + (size_t)(p & 0xFFFF) * 3072;
    int r = p >> 16;
    float v0 = bf2f(xr[t]), v1 = bf2f(xr[t + 256]), v2 = bf2f(xr[t + 512]);
    if (r == 0)      { a00 += v0; a01 += v1; a02 += v2; c0++; }
    else if (r == 1) { a10 += v0; a11 += v1; a12 += v2; c1++; }
    else             { a20 += v0; a21 += v1; a22 += v2; c2++; }
  }
  float i0 = 1.0f / (float)(c0 > 0 ? c0 : 1);
  float i1 = 1.0f / (float)(c1 > 0 ? c1 : 1);
  float i2 = 1.0f / (float)(c2 > 0 ? c2 : 1);
  unsigned short* d = dst + (size_t)i * 3072;
  d[t] = f2bf(a00 * i0); d[t + 256] = f2bf(a01 * i0); d[t + 512] = f2bf(a02 * i0);
  d += F;
  d[t] = f2bf(a10 * i1); d[t + 256] = f2bf(a11 * i1); d[t + 512] = f2bf(a12 * i1);
  d += F;
  d[t] = f2bf(a20 * i2); d[t + 256] = f2bf(a21 * i2); d[t + 512] = f2bf(a22 * i2);
}

// ---------------- bf16 MFMA GEMM, 64x64 tile, BK=64, double-buffered LDS ----------
// C[m][n] = sum_k A[m][k] * Bt[n][k]   (A, Bt bf16 row-major)
// EPI: 0 f32 store | 1 +bias f32 | 2 +bias relu -> f32 C + bf16 C2
//      3 gate-mix -> bf16 C2 only | 4 gate-mix -> f32 C
template <int EPI>
__launch_bounds__(256)
__global__ void kmm(const unsigned short* __restrict__ A, int lda,
                    const unsigned short* __restrict__ B, int ldb,
                    float* __restrict__ C, int ldc, int K,
                    const float* __restrict__ bias,
                    const float* __restrict__ aux1,   // tq (tanh(qi)) f32 [.,768]
                    const float* __restrict__ aux2,   // h f32 [.,768]
                    unsigned short* __restrict__ C2, int ldc2) {
  __shared__ unsigned short Asb[2][64 * 64];
  __shared__ unsigned short Bsb[2][64 * 64];
  const int t = threadIdx.x;
  const int lane = t & 63, wid = t >> 6;
  const int wr = wid >> 1, wc = wid & 1;
  const int bm = blockIdx.x * 64, bn = blockIdx.y * 64;

  // staging geometry: wave w covers rows w*16 + j*8 + (lane>>3); chunk (lane&7)
  // LDS is stored linearly; global source k-chunk pre-swizzled: chunk ^= (row&7)
  const int srow = lane >> 3, schunk = lane & 7;
  const int kxor = ((schunk ^ srow) << 3);             // element offset within 64-wide k window
  const int rowA = wid * 16 + srow;
  const unsigned short* Ap = A + (size_t)(bm + rowA) * lda + kxor;
  const unsigned short* Bp = B + (size_t)(bn + rowA) * ldb + kxor;
  const int lbase = wid * 16 * 64;                     // elements

  // fragment-read geometry (swizzled to match)
  const int rA0 = wr * 32 + (lane & 15);
  const int rB0 = wc * 32 + (lane & 15);
  const int l7 = lane & 7, lq = lane >> 4;
  const int s8_0 = (((0 * 4 + lq) ^ l7) << 3);
  const int s8_1 = (((1 * 4 + lq) ^ l7) << 3);

  f32x4 acc[2][2] = {};

  auto stage = [&](int cb, int k0) {
#pragma unroll
    for (int j = 0; j < 2; ++j) {
      gload16(Ap + (size_t)j * 8 * lda + k0, &Asb[cb][lbase + j * 512]);
      gload16(Bp + (size_t)j * 8 * ldb + k0, &Bsb[cb][lbase + j * 512]);
    }
  };

  stage(0, 0);
  __syncthreads();
  int cur = 0;
  for (int k0 = 0; k0 < K; k0 += 64) {
    if (k0 + 64 < K) stage(cur ^ 1, k0 + 64);
    const unsigned short* As = Asb[cur];
    const unsigned short* Bs = Bsb[cur];
#pragma unroll
    for (int ks = 0; ks < 2; ++ks) {
      const int s8 = ks ? s8_1 : s8_0;
      s16x8 af[2], bf[2];
#pragma unroll
      for (int i = 0; i < 2; ++i)
        af[i] = *(const s16x8*)(As + (rA0 + i * 16) * 64 + s8);
#pragma unroll
      for (int n = 0; n < 2; ++n)
        bf[n] = *(const s16x8*)(Bs + (rB0 + n * 16) * 64 + s8);
#pragma unroll
      for (int i = 0; i < 2; ++i)
#pragma unroll
        for (int n = 0; n < 2; ++n)
          acc[i][n] = __builtin_amdgcn_mfma_f32_16x16x32_bf16(af[i], bf[n], acc[i][n], 0, 0, 0);
    }
    __syncthreads();
    cur ^= 1;
  }

#pragma unroll
  for (int i = 0; i < 2; ++i)
#pragma unroll
    for (int n = 0; n < 2; ++n)
#pragma unroll
      for (int j = 0; j < 4; ++j) {
        const int row = bm + wr * 32 + i * 16 + (lane >> 4) * 4 + j;
        const int col = bn + wc * 32 + n * 16 + (lane & 15);
        float v = acc[i][n][j];
        if (EPI == 1 || EPI == 2) v += bias[col];
        if (EPI == 2) {
          v = fmaxf(v, 0.0f);
          C2[(size_t)row * ldc2 + col] = f2bf(v);
          C[(size_t)row * ldc + col] = v;
        } else if (EPI == 3 || EPI == 4) {
          float z = v + bias[col];
          float al = 1.0f / (1.0f + __expf(-z));
          float tq = aux1[(size_t)row * F + col];
          float hv = aux2[(size_t)row * F + col];
          float o = al * tq + (1.0f - al) * hv;
          if (EPI == 3) C2[(size_t)row * ldc2 + col] = f2bf(o);
          else          C[(size_t)row * ldc + col] = o;
        } else {
          C[(size_t)row * ldc + col] = v;
        }
      }
}

// ---------------- qi = sum_l sigmoid(hg+qg) * q; writes bf16 qi -> hqcat right,
// tanh(qi) -> tq (in-place over hg) ----------------
__global__ void kqi(const float* __restrict__ hg, const float* __restrict__ q,
                    const float* __restrict__ qg,
                    unsigned short* __restrict__ hq,  // [.,1536], right half filled here
                    float* __restrict__ tq,           // == hg (in-place ok)
                    int npb, int L) {
  const int t = threadIdx.x;
  const int g0 = blockIdx.x * 8;
  const int b = g0 / npb;
  float hgv[8][3], acc[8][3];
#pragma unroll
  for (int nn = 0; nn < 8; ++nn)
#pragma unroll
    for (int c = 0; c < 3; ++c) {
      hgv[nn][c] = hg[(size_t)(g0 + nn) * F + c * 256 + t];
      acc[nn][c] = 0.0f;
    }
  const float* qb = q + (size_t)b * L * F;
  const float* qgb = qg + (size_t)b * L * F;
  for (int l = 0; l < L; ++l) {
    float qr[3], qgr[3];
#pragma unroll
    for (int c = 0; c < 3; ++c) {
      qr[c] = qb[(size_t)l * F + c * 256 + t];
      qgr[c] = qgb[(size_t)l * F + c * 256 + t];
    }
#pragma unroll
    for (int nn = 0; nn < 8; ++nn)
#pragma unroll
      for (int c = 0; c < 3; ++c) {
        float s = 1.0f / (1.0f + __expf(-(hgv[nn][c] + qgr[c])));
        acc[nn][c] = fmaf(s, qr[c], acc[nn][c]);
      }
  }
#pragma unroll
  for (int nn = 0; nn < 8; ++nn)
#pragma unroll
    for (int c = 0; c < 3; ++c) {
      const int g = g0 + nn, cc = c * 256 + t;
      hq[(size_t)g * 1536 + F + cc] = f2bf(acc[nn][c]);
      tq[(size_t)g * F + cc] = tanhf(acc[nn][c]);
    }
}

// ---------------- launch ----------------
extern "C" void kernel_launch(void* const* d_in, const int* in_sizes, int n_in,
                              void* d_out, int out_size, void* d_ws, size_t ws_size,
                              hipStream_t stream) {
  const float* x = (const float*)d_in[0];
  const int* ei = (const int*)d_in[1];
  const int* et = (const int*)d_in[2];
  const float* q = (const float*)d_in[3];
  const float* Wrel1 = (const float*)d_in[4];
  const float* Wroot1 = (const float*)d_in[5];
  const float* b1 = (const float*)d_in[6];
  const float* Wrel2 = (const float*)d_in[7];
  const float* Wroot2 = (const float*)d_in[8];
  const float* b2 = (const float*)d_in[9];
  const float* Wg = (const float*)d_in[10];
  const float* bg = (const float*)d_in[11];
  const float* Wq = (const float*)d_in[12];
  const float* bq = (const float*)d_in[13];

  const int BNn = in_sizes[0] / F;       // 2048
  const int E = in_sizes[1] / 2;         // 65536
  const int L = 64;
  const int Bq = in_sizes[3] / (L * F);  // 8
  const int npb = BNn / Bq;              // 256
  const int ML = Bq * L;                 // 512
  float* out = (float*)d_out;

  char* p = (char*)d_ws;
  auto alloc = [&](size_t bytes) {
    void* r = (void*)p;
    p += (bytes + 255) & ~(size_t)255;
    return r;
  };
  int* cnt = (int*)alloc((size_t)BNn * 4);
  int* cur = (int*)alloc((size_t)BNn * 4);
  int* offs = (int*)alloc((size_t)(BNn + 1) * 4);
  int* sorted = (int*)alloc((size_t)E * 4);
  unsigned short* Acat = (unsigned short*)alloc((size_t)BNn * 3072 * 2);
  unsigned short* Wcat1 = (unsigned short*)alloc((size_t)F * 3072 * 2);
  unsigned short* Wcat2 = (unsigned short*)alloc((size_t)F * 3072 * 2);
  unsigned short* Wgbf = (unsigned short*)alloc((size_t)F * 1536 * 2);
  unsigned short* Wqbf = (unsigned short*)alloc((size_t)F * 1536 * 2);
  unsigned short* qbf = (unsigned short*)alloc((size_t)ML * F * 2);
  float* qg = (float*)alloc((size_t)ML * F * 4);
  float* h = (float*)alloc((size_t)BNn * F * 4);
  float* hg = (float*)alloc((size_t)BNn * F * 4);  // reused as tq in-place
  unsigned short* hqcat = (unsigned short*)alloc((size_t)BNn * 1536 * 2);

  hipMemsetAsync(cnt, 0, (size_t)BNn * 4, stream);
  hipMemsetAsync(cur, 0, (size_t)BNn * 4, stream);
  khist<<<(E + 255) / 256, 256, 0, stream>>>(ei, E, cnt);
  kscan<<<1, 256, 0, stream>>>(cnt, offs, BNn);
  kscatter<<<(E + 255) / 256, 256, 0, stream>>>(ei, et, E, offs, cur, sorted);

  // weight / activation prep (bf16)
  kcvt<<<BNn, F / 4, 0, stream>>>(x, Acat, 3072);       // Acat left = bf16(x)
  kcvt<<<ML, F / 4, 0, stream>>>(q, qbf, F);
  kcvt<<<F, 1536 / 4, 0, stream>>>(Wg, Wgbf, 1536);
  kcvt<<<F, 1536 / 4, 0, stream>>>(Wq, Wqbf, 1536);
  ktrans<<<dim3(12, 12, 8), 256, 0, stream>>>(Wroot1, Wrel1, Wroot2, Wrel2, Wcat1, Wcat2);

  // qg = q @ Wg[:,F:].T + bg  (once, reused by both gates)
  kmm<1><<<dim3(ML / 64, F / 64), 256, 0, stream>>>(
      qbf, F, Wgbf + F, 1536, qg, F, F, bg, nullptr, nullptr, nullptr, 0);

  dim3 gBig(BNn / 64, F / 64);  // 32 x 12

  for (int layer = 0; layer < 2; ++layer) {
    const unsigned short* Wcat = layer ? Wcat2 : Wcat1;
    const float* bb = layer ? b2 : b1;

    // Acat right = per-relation means of Acat left
    kagg<<<BNn, 256, 0, stream>>>(offs, sorted, Acat, Acat + F);

    // h = relu(Acat @ Wcat.T + b); dual-store f32 h + bf16 -> hqcat left
    kmm<2><<<gBig, 256, 0, stream>>>(Acat, 3072, Wcat, 3072, h, F, 3072, bb,
                                     nullptr, nullptr, hqcat, 1536);

    // hg = h @ Wg[:,:F].T
    kmm<0><<<gBig, 256, 0, stream>>>(hqcat, 1536, Wgbf, 1536, hg, F, F,
                                     nullptr, nullptr, nullptr, nullptr, 0);

    // qi, tanh(qi); fills hqcat right half, tq over hg
    kqi<<<BNn / 8, 256, 0, stream>>>(hg, q, qg, hqcat, hg, npb, L);

    // gate: z = [h|qi] @ Wq.T + bq; out = sig(z)*tanh(qi) + (1-sig(z))*h
    if (layer == 0) {
      // write bf16 result directly into Acat left for layer 2
      kmm<3><<<gBig, 256, 0, stream>>>(hqcat, 1536, Wqbf, 1536, nullptr, 0, 1536,
                                       bq, hg, h, Acat, 3072);
    } else {
      kmm<4><<<gBig, 256, 0, stream>>>(hqcat, 1536, Wqbf, 1536, out, F, 1536,
                                       bq, hg, h, nullptr, 0);
    }
  }
}

// Round 3
// 364.780 us; speedup vs baseline: 2.8847x; 1.2734x over previous
//
#include <hip/hip_runtime.h>
#include <hip/hip_bf16.h>
#include <cstdint>
#include <cstddef>

#define F 768

typedef float f32x4 __attribute__((ext_vector_type(4)));
typedef short s16x8 __attribute__((ext_vector_type(8)));
typedef short s16x4 __attribute__((ext_vector_type(4)));

#define NEG_LOG2E (-1.4426950408889634f)

__device__ __forceinline__ float bf2f(unsigned short u) {
  union { unsigned int i; float f; } v; v.i = ((unsigned int)u) << 16; return v.f;
}
__device__ __forceinline__ unsigned short f2bf(float f) {
  union { float f; unsigned int i; } v; v.f = f;
  unsigned int r = v.i + 0x7FFF + ((v.i >> 16) & 1);  // RNE
  return (unsigned short)(r >> 16);
}

#if __has_builtin(__builtin_amdgcn_exp2f)
__device__ __forceinline__ float fexp2(float x) { return __builtin_amdgcn_exp2f(x); }
#else
__device__ __forceinline__ float fexp2(float x) { return exp2f(x); }
#endif
#if __has_builtin(__builtin_amdgcn_rcpf)
__device__ __forceinline__ float frcp(float x) { return __builtin_amdgcn_rcpf(x); }
#else
__device__ __forceinline__ float frcp(float x) { return 1.0f / x; }
#endif

// tanh via exp2: (t-1)/(t+1), t = 2^(2x*log2e); saturates correctly at +-inf
__device__ __forceinline__ float ftanh(float x) {
  float t = fexp2(x * 2.8853900817779268f);
  float s = frcp(t + 1.0f);
  return fmaf(-2.0f, s, 1.0f);
}

__device__ __forceinline__ void gload16(const void* g, void* l) {
  __builtin_amdgcn_global_load_lds(
      (const __attribute__((address_space(1))) void*)g,
      (__attribute__((address_space(3))) void*)l, 16, 0, 0);
}

// ---------------- CSR build (edges sorted by dst) ----------------
__global__ void khist(const int* __restrict__ ei, int E, int* __restrict__ cnt) {
  int e = blockIdx.x * blockDim.x + threadIdx.x;
  if (e < E) atomicAdd(&cnt[ei[E + e]], 1);
}

__global__ void kscan(const int* __restrict__ cnt, int* __restrict__ offs, int n) {
  __shared__ int part[256];
  int t = threadIdx.x;
  const int per = n / 256;  // 8
  int local[8];
  int s = 0;
  for (int j = 0; j < per; ++j) { local[j] = cnt[t * per + j]; s += local[j]; }
  part[t] = s;
  __syncthreads();
  for (int d = 1; d < 256; d <<= 1) {
    int v = (t >= d) ? part[t - d] : 0;
    __syncthreads();
    part[t] += v;
    __syncthreads();
  }
  int run = (t == 0) ? 0 : part[t - 1];
  for (int j = 0; j < per; ++j) { offs[t * per + j] = run; run += local[j]; }
  if (t == 255) offs[n] = run;
}

__global__ void kscatter(const int* __restrict__ ei, const int* __restrict__ et, int E,
                         const int* __restrict__ offs, int* __restrict__ cur,
                         int* __restrict__ sorted) {
  int e = blockIdx.x * blockDim.x + threadIdx.x;
  if (e >= E) return;
  int dst = ei[E + e];
  int pos = offs[dst] + atomicAdd(&cur[dst], 1);
  sorted[pos] = ei[e] | (et[e] << 16);
}

// ---------------- weight prep ----------------
__global__ void kcvt(const float* __restrict__ src, unsigned short* __restrict__ dst, int ldd) {
  const int r = blockIdx.x;
  const int cols = blockDim.x * 4;
  const int c = threadIdx.x * 4;
  float4 v = *(const float4*)(src + (size_t)r * cols + c);
  s16x4 o;
  o[0] = (short)f2bf(v.x); o[1] = (short)f2bf(v.y);
  o[2] = (short)f2bf(v.z); o[3] = (short)f2bf(v.w);
  *(s16x4*)(dst + (size_t)r * ldd + c) = o;
}

// transpose-convert: Wcat_l[n][part*768 + k] = Wpart[k][n], grid (12,12,8)
__global__ void ktrans(const float* __restrict__ Wr1, const float* __restrict__ Wl1,
                       const float* __restrict__ Wr2, const float* __restrict__ Wl2,
                       unsigned short* __restrict__ Wcat1, unsigned short* __restrict__ Wcat2) {
  __shared__ float tile[64][65];
  const int z = blockIdx.z, layer = z >> 2, part = z & 3;
  const float* src = (part == 0) ? (layer ? Wr2 : Wr1)
                                 : ((layer ? Wl2 : Wl1) + (size_t)(part - 1) * F * F);
  unsigned short* dst = (layer ? Wcat2 : Wcat1) + part * F;
  const int kt = blockIdx.x * 64, nt = blockIdx.y * 64;
  const int t = threadIdx.x, c = t & 63, r4 = t >> 6;
#pragma unroll
  for (int it = 0; it < 16; ++it) {
    int kk = r4 + it * 4;
    tile[kk][c] = src[(size_t)(kt + kk) * F + nt + c];
  }
  __syncthreads();
#pragma unroll
  for (int it = 0; it < 16; ++it) {
    int rr = r4 + it * 4;
    dst[(size_t)(nt + rr) * 3072 + kt + c] = f2bf(tile[c][rr]);
  }
}

// ---------------- per-(dst,relation) mean ----------------
__global__ void kagg(const int* __restrict__ offs, const int* __restrict__ sorted,
                     const unsigned short* __restrict__ hin,   // Acat left, ld 3072
                     unsigned short* __restrict__ dst) {       // Acat + 768, ld 3072
  const int i = blockIdx.x, t = threadIdx.x;
  float a00 = 0, a01 = 0, a02 = 0, a10 = 0, a11 = 0, a12 = 0, a20 = 0, a21 = 0, a22 = 0;
  int c0 = 0, c1 = 0, c2 = 0;
  const int beg = offs[i], end = offs[i + 1];
  for (int e = beg; e < end; ++e) {
    int p = sorted[e];
    const unsigned short* xr = hin + (size_t)(p & 0xFFFF) * 3072;
    int r = p >> 16;
    float v0 = bf2f(xr[t]), v1 = bf2f(xr[t + 256]), v2 = bf2f(xr[t + 512]);
    if (r == 0)      { a00 += v0; a01 += v1; a02 += v2; c0++; }
    else if (r == 1) { a10 += v0; a11 += v1; a12 += v2; c1++; }
    else             { a20 += v0; a21 += v1; a22 += v2; c2++; }
  }
  float i0 = 1.0f / (float)(c0 > 0 ? c0 : 1);
  float i1 = 1.0f / (float)(c1 > 0 ? c1 : 1);
  float i2 = 1.0f / (float)(c2 > 0 ? c2 : 1);
  unsigned short* d = dst + (size_t)i * 3072;
  d[t] = f2bf(a00 * i0); d[t + 256] = f2bf(a01 * i0); d[t + 512] = f2bf(a02 * i0);
  d += F;
  d[t] = f2bf(a10 * i1); d[t + 256] = f2bf(a11 * i1); d[t + 512] = f2bf(a12 * i1);
  d += F;
  d[t] = f2bf(a20 * i2); d[t + 256] = f2bf(a21 * i2); d[t + 512] = f2bf(a22 * i2);
}

// ---------------- bf16 MFMA GEMM, 64x64 tile, BK=64, double-buffered LDS ----------
// EPI: 0 f32 store | 1 +bias f32 | 2 +bias relu -> f32 C + bf16 C2
//      3 gate-mix -> bf16 C2 only | 4 gate-mix -> f32 C
//      5 v*escale -> f32 | 6 (v+bias)*escale -> f32
template <int EPI>
__launch_bounds__(256)
__global__ void kmm(const unsigned short* __restrict__ A, int lda,
                    const unsigned short* __restrict__ B, int ldb,
                    float* __restrict__ C, int ldc, int K,
                    const float* __restrict__ bias,
                    const float* __restrict__ aux1,   // tq (tanh(qi)) f32 [.,768]
                    const float* __restrict__ aux2,   // h f32 [.,768]
                    unsigned short* __restrict__ C2, int ldc2, float escale) {
  __shared__ unsigned short Asb[2][64 * 64];
  __shared__ unsigned short Bsb[2][64 * 64];
  const int t = threadIdx.x;
  const int lane = t & 63, wid = t >> 6;
  const int wr = wid >> 1, wc = wid & 1;
  const int bm = blockIdx.x * 64, bn = blockIdx.y * 64;

  const int srow = lane >> 3, schunk = lane & 7;
  const int kxor = ((schunk ^ srow) << 3);
  const int rowA = wid * 16 + srow;
  const unsigned short* Ap = A + (size_t)(bm + rowA) * lda + kxor;
  const unsigned short* Bp = B + (size_t)(bn + rowA) * ldb + kxor;
  const int lbase = wid * 16 * 64;

  const int rA0 = wr * 32 + (lane & 15);
  const int rB0 = wc * 32 + (lane & 15);
  const int l7 = lane & 7, lq = lane >> 4;
  const int s8_0 = (((0 * 4 + lq) ^ l7) << 3);
  const int s8_1 = (((1 * 4 + lq) ^ l7) << 3);

  f32x4 acc[2][2] = {};

  auto stage = [&](int cb, int k0) {
#pragma unroll
    for (int j = 0; j < 2; ++j) {
      gload16(Ap + (size_t)j * 8 * lda + k0, &Asb[cb][lbase + j * 512]);
      gload16(Bp + (size_t)j * 8 * ldb + k0, &Bsb[cb][lbase + j * 512]);
    }
  };

  stage(0, 0);
  __syncthreads();
  int cur = 0;
  for (int k0 = 0; k0 < K; k0 += 64) {
    if (k0 + 64 < K) stage(cur ^ 1, k0 + 64);
    const unsigned short* As = Asb[cur];
    const unsigned short* Bs = Bsb[cur];
#pragma unroll
    for (int ks = 0; ks < 2; ++ks) {
      const int s8 = ks ? s8_1 : s8_0;
      s16x8 af[2], bf[2];
#pragma unroll
      for (int i = 0; i < 2; ++i)
        af[i] = *(const s16x8*)(As + (rA0 + i * 16) * 64 + s8);
#pragma unroll
      for (int n = 0; n < 2; ++n)
        bf[n] = *(const s16x8*)(Bs + (rB0 + n * 16) * 64 + s8);
#pragma unroll
      for (int i = 0; i < 2; ++i)
#pragma unroll
        for (int n = 0; n < 2; ++n)
          acc[i][n] = __builtin_amdgcn_mfma_f32_16x16x32_bf16(af[i], bf[n], acc[i][n], 0, 0, 0);
    }
    __syncthreads();
    cur ^= 1;
  }

#pragma unroll
  for (int i = 0; i < 2; ++i)
#pragma unroll
    for (int n = 0; n < 2; ++n)
#pragma unroll
      for (int j = 0; j < 4; ++j) {
        const int row = bm + wr * 32 + i * 16 + (lane >> 4) * 4 + j;
        const int col = bn + wc * 32 + n * 16 + (lane & 15);
        float v = acc[i][n][j];
        if (EPI == 1 || EPI == 2) v += bias[col];
        if (EPI == 2) {
          v = fmaxf(v, 0.0f);
          C2[(size_t)row * ldc2 + col] = f2bf(v);
          C[(size_t)row * ldc + col] = v;
        } else if (EPI == 3 || EPI == 4) {
          float z = v + bias[col];
          float al = frcp(1.0f + fexp2(z * NEG_LOG2E));
          float tq = aux1[(size_t)row * F + col];
          float hv = aux2[(size_t)row * F + col];
          float o = al * tq + (1.0f - al) * hv;
          if (EPI == 3) C2[(size_t)row * ldc2 + col] = f2bf(o);
          else          C[(size_t)row * ldc + col] = o;
        } else if (EPI == 5) {
          C[(size_t)row * ldc + col] = v * escale;
        } else if (EPI == 6) {
          C[(size_t)row * ldc + col] = (v + bias[col]) * escale;
        } else {
          C[(size_t)row * ldc + col] = v;
        }
      }
}

// ---------------- qi = sum_l sigmoid * q ----------------
// hgp, qgp are PRE-SCALED by -log2e (so sigmoid = rcp(1 + exp2(hgp+qgp))).
// 2 nodes/block -> 1024 blocks -> 4 waves/SIMD.
__global__ void kqi(const float* __restrict__ hgp, const float* __restrict__ q,
                    const float* __restrict__ qgp,
                    unsigned short* __restrict__ hq,  // [.,1536], right half filled here
                    float* __restrict__ tq,           // == hgp buffer (in-place ok)
                    int npb, int L) {
  const int t = threadIdx.x;
  const int g0 = blockIdx.x * 2;
  const int b = g0 / npb;
  float hgv[2][3], acc[2][3];
#pragma unroll
  for (int nn = 0; nn < 2; ++nn)
#pragma unroll
    for (int c = 0; c < 3; ++c) {
      hgv[nn][c] = hgp[(size_t)(g0 + nn) * F + c * 256 + t];
      acc[nn][c] = 0.0f;
    }
  const float* qb = q + (size_t)b * L * F;
  const float* qgb = qgp + (size_t)b * L * F;
#pragma unroll 4
  for (int l = 0; l < L; ++l) {
    float qr[3], qgr[3];
#pragma unroll
    for (int c = 0; c < 3; ++c) {
      qr[c] = qb[(size_t)l * F + c * 256 + t];
      qgr[c] = qgb[(size_t)l * F + c * 256 + t];
    }
#pragma unroll
    for (int nn = 0; nn < 2; ++nn)
#pragma unroll
      for (int c = 0; c < 3; ++c) {
        float s = frcp(1.0f + fexp2(hgv[nn][c] + qgr[c]));
        acc[nn][c] = fmaf(s, qr[c], acc[nn][c]);
      }
  }
#pragma unroll
  for (int nn = 0; nn < 2; ++nn)
#pragma unroll
    for (int c = 0; c < 3; ++c) {
      const int g = g0 + nn, cc = c * 256 + t;
      hq[(size_t)g * 1536 + F + cc] = f2bf(acc[nn][c]);
      tq[(size_t)g * F + cc] = ftanh(acc[nn][c]);
    }
}

// ---------------- launch ----------------
extern "C" void kernel_launch(void* const* d_in, const int* in_sizes, int n_in,
                              void* d_out, int out_size, void* d_ws, size_t ws_size,
                              hipStream_t stream) {
  const float* x = (const float*)d_in[0];
  const int* ei = (const int*)d_in[1];
  const int* et = (const int*)d_in[2];
  const float* q = (const float*)d_in[3];
  const float* Wrel1 = (const float*)d_in[4];
  const float* Wroot1 = (const float*)d_in[5];
  const float* b1 = (const float*)d_in[6];
  const float* Wrel2 = (const float*)d_in[7];
  const float* Wroot2 = (const float*)d_in[8];
  const float* b2 = (const float*)d_in[9];
  const float* Wg = (const float*)d_in[10];
  const float* bg = (const float*)d_in[11];
  const float* Wq = (const float*)d_in[12];
  const float* bq = (const float*)d_in[13];

  const int BNn = in_sizes[0] / F;       // 2048
  const int E = in_sizes[1] / 2;         // 65536
  const int L = 64;
  const int Bq = in_sizes[3] / (L * F);  // 8
  const int npb = BNn / Bq;              // 256
  const int ML = Bq * L;                 // 512
  float* out = (float*)d_out;

  char* p = (char*)d_ws;
  auto alloc = [&](size_t bytes) {
    void* r = (void*)p;
    p += (bytes + 255) & ~(size_t)255;
    return r;
  };
  int* cnt = (int*)alloc((size_t)BNn * 4);
  int* cur = (int*)alloc((size_t)BNn * 4);
  int* offs = (int*)alloc((size_t)(BNn + 1) * 4);
  int* sorted = (int*)alloc((size_t)E * 4);
  unsigned short* Acat = (unsigned short*)alloc((size_t)BNn * 3072 * 2);
  unsigned short* Wcat1 = (unsigned short*)alloc((size_t)F * 3072 * 2);
  unsigned short* Wcat2 = (unsigned short*)alloc((size_t)F * 3072 * 2);
  unsigned short* Wgbf = (unsigned short*)alloc((size_t)F * 1536 * 2);
  unsigned short* Wqbf = (unsigned short*)alloc((size_t)F * 1536 * 2);
  unsigned short* qbf = (unsigned short*)alloc((size_t)ML * F * 2);
  float* qg = (float*)alloc((size_t)ML * F * 4);
  float* h = (float*)alloc((size_t)BNn * F * 4);
  float* hg = (float*)alloc((size_t)BNn * F * 4);  // reused as tq in-place
  unsigned short* hqcat = (unsigned short*)alloc((size_t)BNn * 1536 * 2);

  hipMemsetAsync(cnt, 0, (size_t)BNn * 4, stream);
  hipMemsetAsync(cur, 0, (size_t)BNn * 4, stream);
  khist<<<(E + 255) / 256, 256, 0, stream>>>(ei, E, cnt);
  kscan<<<1, 256, 0, stream>>>(cnt, offs, BNn);
  kscatter<<<(E + 255) / 256, 256, 0, stream>>>(ei, et, E, offs, cur, sorted);

  kcvt<<<BNn, F / 4, 0, stream>>>(x, Acat, 3072);  // Acat left = bf16(x)
  kcvt<<<ML, F / 4, 0, stream>>>(q, qbf, F);
  kcvt<<<F, 1536 / 4, 0, stream>>>(Wg, Wgbf, 1536);
  kcvt<<<F, 1536 / 4, 0, stream>>>(Wq, Wqbf, 1536);
  ktrans<<<dim3(12, 12, 8), 256, 0, stream>>>(Wroot1, Wrel1, Wroot2, Wrel2, Wcat1, Wcat2);

  // qg' = -(q @ Wg[:,F:].T + bg) * log2e  (once, reused by both gates)
  kmm<6><<<dim3(ML / 64, F / 64), 256, 0, stream>>>(
      qbf, F, Wgbf + F, 1536, qg, F, F, bg, nullptr, nullptr, nullptr, 0, NEG_LOG2E);

  dim3 gBig(BNn / 64, F / 64);  // 32 x 12

  for (int layer = 0; layer < 2; ++layer) {
    const unsigned short* Wcat = layer ? Wcat2 : Wcat1;
    const float* bb = layer ? b2 : b1;

    kagg<<<BNn, 256, 0, stream>>>(offs, sorted, Acat, Acat + F);

    // h = relu(Acat @ Wcat.T + b); dual-store f32 h + bf16 -> hqcat left
    kmm<2><<<gBig, 256, 0, stream>>>(Acat, 3072, Wcat, 3072, h, F, 3072, bb,
                                     nullptr, nullptr, hqcat, 1536, 0.f);

    // hg' = -(h @ Wg[:,:F].T) * log2e
    kmm<5><<<gBig, 256, 0, stream>>>(hqcat, 1536, Wgbf, 1536, hg, F, F,
                                     nullptr, nullptr, nullptr, nullptr, 0, NEG_LOG2E);

    // qi, tanh(qi); fills hqcat right half, tq over hg
    kqi<<<BNn / 2, 256, 0, stream>>>(hg, q, qg, hqcat, hg, npb, L);

    // gate: z = [h|qi] @ Wq.T + bq; out = sig(z)*tanh(qi) + (1-sig(z))*h
    if (layer == 0) {
      kmm<3><<<gBig, 256, 0, stream>>>(hqcat, 1536, Wqbf, 1536, nullptr, 0, 1536,
                                       bq, hg, h, Acat, 3072, 0.f);
    } else {
      kmm<4><<<gBig, 256, 0, stream>>>(hqcat, 1536, Wqbf, 1536, out, F, 1536,
                                       bq, hg, h, nullptr, 0, 0.f);
    }
  }
}

// Round 4
// 338.070 us; speedup vs baseline: 3.1127x; 1.0790x over previous
//
#include <hip/hip_runtime.h>
#include <hip/hip_bf16.h>
#include <cstdint>
#include <cstddef>

#define F 768

typedef float f32x4 __attribute__((ext_vector_type(4)));
typedef short s16x8 __attribute__((ext_vector_type(8)));
typedef short s16x4 __attribute__((ext_vector_type(4)));

#define NEG_LOG2E (-1.4426950408889634f)

__device__ __forceinline__ float bf2f(unsigned short u) {
  union { unsigned int i; float f; } v; v.i = ((unsigned int)u) << 16; return v.f;
}
__device__ __forceinline__ unsigned short f2bf(float f) {
  union { float f; unsigned int i; } v; v.f = f;
  unsigned int r = v.i + 0x7FFF + ((v.i >> 16) & 1);  // RNE
  return (unsigned short)(r >> 16);
}

#if __has_builtin(__builtin_amdgcn_exp2f)
__device__ __forceinline__ float fexp2(float x) { return __builtin_amdgcn_exp2f(x); }
#else
__device__ __forceinline__ float fexp2(float x) { return exp2f(x); }
#endif
#if __has_builtin(__builtin_amdgcn_rcpf)
__device__ __forceinline__ float frcp(float x) { return __builtin_amdgcn_rcpf(x); }
#else
__device__ __forceinline__ float frcp(float x) { return 1.0f / x; }
#endif

__device__ __forceinline__ float ftanh(float x) {
  float t = fexp2(x * 2.8853900817779268f);
  float s = frcp(t + 1.0f);
  return fmaf(-2.0f, s, 1.0f);
}

__device__ __forceinline__ void gload16(const void* g, void* l) {
  __builtin_amdgcn_global_load_lds(
      (const __attribute__((address_space(1))) void*)g,
      (__attribute__((address_space(3))) void*)l, 16, 0, 0);
}

// ---------------- CSR build ----------------
__global__ void khist(const int* __restrict__ ei, int E, int* __restrict__ cnt) {
  int e = blockIdx.x * blockDim.x + threadIdx.x;
  if (e < E) atomicAdd(&cnt[ei[E + e]], 1);
}

__global__ void kscan(const int* __restrict__ cnt, int* __restrict__ offs, int n) {
  __shared__ int part[256];
  int t = threadIdx.x;
  const int per = n / 256;  // 8
  int local[8];
  int s = 0;
  for (int j = 0; j < per; ++j) { local[j] = cnt[t * per + j]; s += local[j]; }
  part[t] = s;
  __syncthreads();
  for (int d = 1; d < 256; d <<= 1) {
    int v = (t >= d) ? part[t - d] : 0;
    __syncthreads();
    part[t] += v;
    __syncthreads();
  }
  int run = (t == 0) ? 0 : part[t - 1];
  for (int j = 0; j < per; ++j) { offs[t * per + j] = run; run += local[j]; }
  if (t == 255) offs[n] = run;
}

__global__ void kscatter(const int* __restrict__ ei, const int* __restrict__ et, int E,
                         const int* __restrict__ offs, int* __restrict__ cur,
                         int* __restrict__ sorted) {
  int e = blockIdx.x * blockDim.x + threadIdx.x;
  if (e >= E) return;
  int dst = ei[E + e];
  int pos = offs[dst] + atomicAdd(&cur[dst], 1);
  sorted[pos] = ei[e] | (et[e] << 16);
}

// ---------------- prep: f32 -> bf16 row convert (192 thr, 4 cols/thr, 768 cols) ----
__global__ void kcvt(const float* __restrict__ src, int lds_,
                     unsigned short* __restrict__ dst, int ldd) {
  const int r = blockIdx.x, c = threadIdx.x * 4;
  float4 v = *(const float4*)(src + (size_t)r * lds_ + c);
  s16x4 o;
  o[0] = (short)f2bf(v.x); o[1] = (short)f2bf(v.y);
  o[2] = (short)f2bf(v.z); o[3] = (short)f2bf(v.w);
  *(s16x4*)(dst + (size_t)r * ldd + c) = o;
}

// gate-weight prep: Wgq[1536][768] = rows of Wg[:, :F] then Wq[:, :F];
// WgR[768][768] = Wg[:, F:]; WqR[768][768] = Wq[:, F:]. grid 3072 x 192 thr.
__global__ void kcvtw(const float* __restrict__ Wg, const float* __restrict__ Wq,
                      unsigned short* __restrict__ Wgq, unsigned short* __restrict__ WgR,
                      unsigned short* __restrict__ WqR) {
  const int b = blockIdx.x, c = threadIdx.x * 4;
  const float* srow;
  unsigned short* drow;
  int off;
  if (b < 1536) {
    srow = (b < 768) ? Wg + (size_t)b * 1536 : Wq + (size_t)(b - 768) * 1536;
    drow = Wgq + (size_t)b * 768;
    off = 0;
  } else if (b < 2304) {
    srow = Wg + (size_t)(b - 1536) * 1536;
    drow = WgR + (size_t)(b - 1536) * 768;
    off = 768;
  } else {
    srow = Wq + (size_t)(b - 2304) * 1536;
    drow = WqR + (size_t)(b - 2304) * 768;
    off = 768;
  }
  float4 v = *(const float4*)(srow + off + c);
  s16x4 o;
  o[0] = (short)f2bf(v.x); o[1] = (short)f2bf(v.y);
  o[2] = (short)f2bf(v.z); o[3] = (short)f2bf(v.w);
  *(s16x4*)(drow + c) = o;
}

// transpose-convert: Wcat_l[n][part*768 + k] = Wpart[k][n], grid (12,12,8)
__global__ void ktrans(const float* __restrict__ Wr1, const float* __restrict__ Wl1,
                       const float* __restrict__ Wr2, const float* __restrict__ Wl2,
                       unsigned short* __restrict__ Wcat1, unsigned short* __restrict__ Wcat2) {
  __shared__ float tile[64][65];
  const int z = blockIdx.z, layer = z >> 2, part = z & 3;
  const float* src = (part == 0) ? (layer ? Wr2 : Wr1)
                                 : ((layer ? Wl2 : Wl1) + (size_t)(part - 1) * F * F);
  unsigned short* dst = (layer ? Wcat2 : Wcat1) + part * F;
  const int kt = blockIdx.x * 64, nt = blockIdx.y * 64;
  const int t = threadIdx.x, c = t & 63, r4 = t >> 6;
#pragma unroll
  for (int it = 0; it < 16; ++it) {
    int kk = r4 + it * 4;
    tile[kk][c] = src[(size_t)(kt + kk) * F + nt + c];
  }
  __syncthreads();
#pragma unroll
  for (int it = 0; it < 16; ++it) {
    int rr = r4 + it * 4;
    dst[(size_t)(nt + rr) * 3072 + kt + c] = f2bf(tile[c][rr]);
  }
}

// ---------------- per-(dst,relation) mean; 192 thr, ushort4/lane, unroll 2 ----------
__global__ void kagg(const int* __restrict__ offs, const int* __restrict__ sorted,
                     const unsigned short* __restrict__ hin,   // Acat left, ld 3072
                     unsigned short* __restrict__ dst) {       // Acat + 768
  const int i = blockIdx.x, t = threadIdx.x;
  const int col = t * 4;
  float a0[4] = {}, a1[4] = {}, a2[4] = {};
  int c0 = 0, c1 = 0, c2 = 0;
  const int beg = offs[i], end = offs[i + 1];
  int e = beg;
  for (; e + 1 < end; e += 2) {
    int p0 = sorted[e], p1 = sorted[e + 1];
    s16x4 w0 = *(const s16x4*)(hin + (size_t)(p0 & 0xFFFF) * 3072 + col);
    s16x4 w1 = *(const s16x4*)(hin + (size_t)(p1 & 0xFFFF) * 3072 + col);
    int r0 = p0 >> 16, r1 = p1 >> 16;
    float v0[4], v1[4];
#pragma unroll
    for (int j = 0; j < 4; ++j) {
      v0[j] = bf2f((unsigned short)w0[j]);
      v1[j] = bf2f((unsigned short)w1[j]);
    }
    if (r0 == 0)      { c0++; for (int j = 0; j < 4; ++j) a0[j] += v0[j]; }
    else if (r0 == 1) { c1++; for (int j = 0; j < 4; ++j) a1[j] += v0[j]; }
    else              { c2++; for (int j = 0; j < 4; ++j) a2[j] += v0[j]; }
    if (r1 == 0)      { c0++; for (int j = 0; j < 4; ++j) a0[j] += v1[j]; }
    else if (r1 == 1) { c1++; for (int j = 0; j < 4; ++j) a1[j] += v1[j]; }
    else              { c2++; for (int j = 0; j < 4; ++j) a2[j] += v1[j]; }
  }
  if (e < end) {
    int p0 = sorted[e];
    s16x4 w0 = *(const s16x4*)(hin + (size_t)(p0 & 0xFFFF) * 3072 + col);
    int r0 = p0 >> 16;
    float v0[4];
#pragma unroll
    for (int j = 0; j < 4; ++j) v0[j] = bf2f((unsigned short)w0[j]);
    if (r0 == 0)      { c0++; for (int j = 0; j < 4; ++j) a0[j] += v0[j]; }
    else if (r0 == 1) { c1++; for (int j = 0; j < 4; ++j) a1[j] += v0[j]; }
    else              { c2++; for (int j = 0; j < 4; ++j) a2[j] += v0[j]; }
  }
  const float i0 = frcp((float)(c0 > 0 ? c0 : 1));
  const float i1 = frcp((float)(c1 > 0 ? c1 : 1));
  const float i2 = frcp((float)(c2 > 0 ? c2 : 1));
  unsigned short* d = dst + (size_t)i * 3072 + col;
  s16x4 o;
#pragma unroll
  for (int j = 0; j < 4; ++j) o[j] = (short)f2bf(a0[j] * i0);
  *(s16x4*)d = o;
#pragma unroll
  for (int j = 0; j < 4; ++j) o[j] = (short)f2bf(a1[j] * i1);
  *(s16x4*)(d + F) = o;
#pragma unroll
  for (int j = 0; j < 4; ++j) o[j] = (short)f2bf(a2[j] * i2);
  *(s16x4*)(d + 2 * F) = o;
}

// ---------------- bf16 MFMA GEMM, 64x64 tile, BK=64, dbuf LDS, fused epilogues ----
// EPI: 3 gate-mix -> bf16 C2 | 4 gate-mix -> f32 C
//      5 v * (bn<768 ? escale : 1) -> f32   (GEMM1 col-region scale)
//      6 (v+bias)*escale -> f32             (qg)
template <int EPI>
__launch_bounds__(256)
__global__ void kmm(const unsigned short* __restrict__ A, int lda,
                    const unsigned short* __restrict__ B, int ldb,
                    float* __restrict__ C, int ldc, int K,
                    const float* __restrict__ bias,
                    const float* __restrict__ aux1,          // hgz base (tq | zh), ld 1536
                    const unsigned short* __restrict__ aux2, // hb bf16, ld 768
                    unsigned short* __restrict__ C2, int ldc2, float escale) {
  __shared__ unsigned short Asb[2][64 * 64];
  __shared__ unsigned short Bsb[2][64 * 64];
  const int t = threadIdx.x;
  const int lane = t & 63, wid = t >> 6;
  const int wr = wid >> 1, wc = wid & 1;
  const int bm = blockIdx.x * 64, bn = blockIdx.y * 64;

  const int srow = lane >> 3, schunk = lane & 7;
  const int kxor = ((schunk ^ srow) << 3);
  const int rowA = wid * 16 + srow;
  const unsigned short* Ap = A + (size_t)(bm + rowA) * lda + kxor;
  const unsigned short* Bp = B + (size_t)(bn + rowA) * ldb + kxor;
  const int lbase = wid * 16 * 64;

  const int rA0 = wr * 32 + (lane & 15);
  const int rB0 = wc * 32 + (lane & 15);
  const int l7 = lane & 7, lq = lane >> 4;
  const int s8_0 = (((0 * 4 + lq) ^ l7) << 3);
  const int s8_1 = (((1 * 4 + lq) ^ l7) << 3);

  f32x4 acc[2][2] = {};

  auto stage = [&](int cb, int k0) {
#pragma unroll
    for (int j = 0; j < 2; ++j) {
      gload16(Ap + (size_t)j * 8 * lda + k0, &Asb[cb][lbase + j * 512]);
      gload16(Bp + (size_t)j * 8 * ldb + k0, &Bsb[cb][lbase + j * 512]);
    }
  };

  stage(0, 0);
  __syncthreads();
  int cur = 0;
  for (int k0 = 0; k0 < K; k0 += 64) {
    if (k0 + 64 < K) stage(cur ^ 1, k0 + 64);
    const unsigned short* As = Asb[cur];
    const unsigned short* Bs = Bsb[cur];
#pragma unroll
    for (int ks = 0; ks < 2; ++ks) {
      const int s8 = ks ? s8_1 : s8_0;
      s16x8 af[2], bf[2];
#pragma unroll
      for (int i = 0; i < 2; ++i)
        af[i] = *(const s16x8*)(As + (rA0 + i * 16) * 64 + s8);
#pragma unroll
      for (int n = 0; n < 2; ++n)
        bf[n] = *(const s16x8*)(Bs + (rB0 + n * 16) * 64 + s8);
#pragma unroll
      for (int i = 0; i < 2; ++i)
#pragma unroll
        for (int n = 0; n < 2; ++n)
          acc[i][n] = __builtin_amdgcn_mfma_f32_16x16x32_bf16(af[i], bf[n], acc[i][n], 0, 0, 0);
    }
    __syncthreads();
    cur ^= 1;
  }

#pragma unroll
  for (int i = 0; i < 2; ++i)
#pragma unroll
    for (int n = 0; n < 2; ++n)
#pragma unroll
      for (int j = 0; j < 4; ++j) {
        const int row = bm + wr * 32 + i * 16 + (lane >> 4) * 4 + j;
        const int col = bn + wc * 32 + n * 16 + (lane & 15);
        float v = acc[i][n][j];
        if (EPI == 3 || EPI == 4) {
          float zh = aux1[(size_t)row * 1536 + 768 + col];
          float z = v + bias[col] + zh;
          float al = frcp(1.0f + fexp2(z * NEG_LOG2E));
          float tq = aux1[(size_t)row * 1536 + col];
          float hv = bf2f(aux2[(size_t)row * 768 + col]);
          float o = al * tq + (1.0f - al) * hv;
          if (EPI == 3) C2[(size_t)row * ldc2 + col] = f2bf(o);
          else          C[(size_t)row * ldc + col] = o;
        } else if (EPI == 5) {
          float es = (bn < 768) ? escale : 1.0f;
          C[(size_t)row * ldc + col] = v * es;
        } else if (EPI == 6) {
          C[(size_t)row * ldc + col] = (v + bias[col]) * escale;
        }
      }
}

// split-K GEMM -> f32 partials. grid (M/64, N/64, S), K-chunk = Ksplit per z.
__launch_bounds__(256)
__global__ void kmm_pk(const unsigned short* __restrict__ A, int lda,
                       const unsigned short* __restrict__ B, int ldb,
                       float* __restrict__ P, int Ksplit, int pstride) {
  __shared__ unsigned short Asb[2][64 * 64];
  __shared__ unsigned short Bsb[2][64 * 64];
  const int t = threadIdx.x;
  const int lane = t & 63, wid = t >> 6;
  const int wr = wid >> 1, wc = wid & 1;
  const int bm = blockIdx.x * 64, bn = blockIdx.y * 64;
  const int kbase = blockIdx.z * Ksplit;
  float* Cp = P + (size_t)blockIdx.z * pstride;

  const int srow = lane >> 3, schunk = lane & 7;
  const int kxor = ((schunk ^ srow) << 3);
  const int rowA = wid * 16 + srow;
  const unsigned short* Ap = A + (size_t)(bm + rowA) * lda + kxor + kbase;
  const unsigned short* Bp = B + (size_t)(bn + rowA) * ldb + kxor + kbase;
  const int lbase = wid * 16 * 64;

  const int rA0 = wr * 32 + (lane & 15);
  const int rB0 = wc * 32 + (lane & 15);
  const int l7 = lane & 7, lq = lane >> 4;
  const int s8_0 = (((0 * 4 + lq) ^ l7) << 3);
  const int s8_1 = (((1 * 4 + lq) ^ l7) << 3);

  f32x4 acc[2][2] = {};

  auto stage = [&](int cb, int k0) {
#pragma unroll
    for (int j = 0; j < 2; ++j) {
      gload16(Ap + (size_t)j * 8 * lda + k0, &Asb[cb][lbase + j * 512]);
      gload16(Bp + (size_t)j * 8 * ldb + k0, &Bsb[cb][lbase + j * 512]);
    }
  };

  stage(0, 0);
  __syncthreads();
  int cur = 0;
  for (int k0 = 0; k0 < Ksplit; k0 += 64) {
    if (k0 + 64 < Ksplit) stage(cur ^ 1, k0 + 64);
    const unsigned short* As = Asb[cur];
    const unsigned short* Bs = Bsb[cur];
#pragma unroll
    for (int ks = 0; ks < 2; ++ks) {
      const int s8 = ks ? s8_1 : s8_0;
      s16x8 af[2], bf[2];
#pragma unroll
      for (int i = 0; i < 2; ++i)
        af[i] = *(const s16x8*)(As + (rA0 + i * 16) * 64 + s8);
#pragma unroll
      for (int n = 0; n < 2; ++n)
        bf[n] = *(const s16x8*)(Bs + (rB0 + n * 16) * 64 + s8);
#pragma unroll
      for (int i = 0; i < 2; ++i)
#pragma unroll
        for (int n = 0; n < 2; ++n)
          acc[i][n] = __builtin_amdgcn_mfma_f32_16x16x32_bf16(af[i], bf[n], acc[i][n], 0, 0, 0);
    }
    __syncthreads();
    cur ^= 1;
  }

#pragma unroll
  for (int i = 0; i < 2; ++i)
#pragma unroll
    for (int n = 0; n < 2; ++n)
#pragma unroll
      for (int j = 0; j < 4; ++j) {
        const int row = bm + wr * 32 + i * 16 + (lane >> 4) * 4 + j;
        const int col = bn + wc * 32 + n * 16 + (lane & 15);
        Cp[(size_t)row * F + col] = acc[i][n][j];
      }
}

// reduce 4 partials + bias -> relu -> bf16 hb. grid 1536 x 256, float4/thr.
__global__ void kep_relu(const float* __restrict__ P, int pstride,
                         const float* __restrict__ bias,
                         unsigned short* __restrict__ hb) {
  const int idx = (blockIdx.x * 256 + threadIdx.x) * 4;
  const int col = idx - (idx / F) * F;
  float4 s = *(const float4*)(P + idx);
  const float4 s1 = *(const float4*)(P + pstride + idx);
  const float4 s2 = *(const float4*)(P + 2 * (size_t)pstride + idx);
  const float4 s3 = *(const float4*)(P + 3 * (size_t)pstride + idx);
  const float4 bv = *(const float4*)(bias + col);
  s.x = fmaxf(s.x + s1.x + s2.x + s3.x + bv.x, 0.0f);
  s.y = fmaxf(s.y + s1.y + s2.y + s3.y + bv.y, 0.0f);
  s.z = fmaxf(s.z + s1.z + s2.z + s3.z + bv.z, 0.0f);
  s.w = fmaxf(s.w + s1.w + s2.w + s3.w + bv.w, 0.0f);
  s16x4 o;
  o[0] = (short)f2bf(s.x); o[1] = (short)f2bf(s.y);
  o[2] = (short)f2bf(s.z); o[3] = (short)f2bf(s.w);
  *(s16x4*)(hb + idx) = o;
}

// ---------------- qi = sum_l sigmoid * q; hg in hgz left (ld 1536) ----------------
__global__ void kqi(float* __restrict__ hgz, const float* __restrict__ q,
                    const float* __restrict__ qgp,
                    unsigned short* __restrict__ qib,  // bf16 [.,768]
                    int npb, int L) {
  const int t = threadIdx.x;
  const int g0 = blockIdx.x * 2;
  const int b = g0 / npb;
  float hgv[2][3], acc[2][3];
#pragma unroll
  for (int nn = 0; nn < 2; ++nn)
#pragma unroll
    for (int c = 0; c < 3; ++c) {
      hgv[nn][c] = hgz[(size_t)(g0 + nn) * 1536 + c * 256 + t];
      acc[nn][c] = 0.0f;
    }
  const float* qb = q + (size_t)b * L * F;
  const float* qgb = qgp + (size_t)b * L * F;
#pragma unroll 4
  for (int l = 0; l < L; ++l) {
    float qr[3], qgr[3];
#pragma unroll
    for (int c = 0; c < 3; ++c) {
      qr[c] = qb[(size_t)l * F + c * 256 + t];
      qgr[c] = qgb[(size_t)l * F + c * 256 + t];
    }
#pragma unroll
    for (int nn = 0; nn < 2; ++nn)
#pragma unroll
      for (int c = 0; c < 3; ++c) {
        float s = frcp(1.0f + fexp2(hgv[nn][c] + qgr[c]));
        acc[nn][c] = fmaf(s, qr[c], acc[nn][c]);
      }
  }
#pragma unroll
  for (int nn = 0; nn < 2; ++nn)
#pragma unroll
    for (int c = 0; c < 3; ++c) {
      const int g = g0 + nn, cc = c * 256 + t;
      qib[(size_t)g * F + cc] = f2bf(acc[nn][c]);
      hgz[(size_t)g * 1536 + cc] = ftanh(acc[nn][c]);  // tq in place over hg
    }
}

// ---------------- launch ----------------
extern "C" void kernel_launch(void* const* d_in, const int* in_sizes, int n_in,
                              void* d_out, int out_size, void* d_ws, size_t ws_size,
                              hipStream_t stream) {
  const float* x = (const float*)d_in[0];
  const int* ei = (const int*)d_in[1];
  const int* et = (const int*)d_in[2];
  const float* q = (const float*)d_in[3];
  const float* Wrel1 = (const float*)d_in[4];
  const float* Wroot1 = (const float*)d_in[5];
  const float* b1 = (const float*)d_in[6];
  const float* Wrel2 = (const float*)d_in[7];
  const float* Wroot2 = (const float*)d_in[8];
  const float* b2 = (const float*)d_in[9];
  const float* Wg = (const float*)d_in[10];
  const float* bg = (const float*)d_in[11];
  const float* Wq = (const float*)d_in[12];
  const float* bq = (const float*)d_in[13];

  const int BNn = in_sizes[0] / F;       // 2048
  const int E = in_sizes[1] / 2;         // 65536
  const int L = 64;
  const int Bq = in_sizes[3] / (L * F);  // 8
  const int npb = BNn / Bq;              // 256
  const int ML = Bq * L;                 // 512
  const int PSTR = BNn * F;              // partial stride (elements)
  float* out = (float*)d_out;

  char* p = (char*)d_ws;
  auto alloc = [&](size_t bytes) {
    void* r = (void*)p;
    p += (bytes + 255) & ~(size_t)255;
    return r;
  };
  int* cnt = (int*)alloc((size_t)BNn * 4);
  int* cur = (int*)alloc((size_t)BNn * 4);
  int* offs = (int*)alloc((size_t)(BNn + 1) * 4);
  int* sorted = (int*)alloc((size_t)E * 4);
  unsigned short* Acat = (unsigned short*)alloc((size_t)BNn * 3072 * 2);
  unsigned short* Wcat1 = (unsigned short*)alloc((size_t)F * 3072 * 2);
  unsigned short* Wcat2 = (unsigned short*)alloc((size_t)F * 3072 * 2);
  unsigned short* Wgq = (unsigned short*)alloc((size_t)1536 * F * 2);
  unsigned short* WgR = (unsigned short*)alloc((size_t)F * F * 2);
  unsigned short* WqR = (unsigned short*)alloc((size_t)F * F * 2);
  unsigned short* qbf = (unsigned short*)alloc((size_t)ML * F * 2);
  float* qg = (float*)alloc((size_t)ML * F * 4);
  unsigned short* hb = (unsigned short*)alloc((size_t)BNn * F * 2);
  float* hgz = (float*)alloc((size_t)BNn * 1536 * 4);
  unsigned short* qib = (unsigned short*)alloc((size_t)BNn * F * 2);
  float* parts = (float*)alloc((size_t)4 * PSTR * 4);

  hipMemsetAsync(cnt, 0, (size_t)BNn * 4, stream);
  hipMemsetAsync(cur, 0, (size_t)BNn * 4, stream);
  khist<<<(E + 255) / 256, 256, 0, stream>>>(ei, E, cnt);
  kscan<<<1, 256, 0, stream>>>(cnt, offs, BNn);
  kscatter<<<(E + 255) / 256, 256, 0, stream>>>(ei, et, E, offs, cur, sorted);

  kcvt<<<BNn, 192, 0, stream>>>(x, F, Acat, 3072);   // Acat left = bf16(x)
  kcvt<<<ML, 192, 0, stream>>>(q, F, qbf, F);
  kcvtw<<<3072, 192, 0, stream>>>(Wg, Wq, Wgq, WgR, WqR);
  ktrans<<<dim3(12, 12, 8), 256, 0, stream>>>(Wroot1, Wrel1, Wroot2, Wrel2, Wcat1, Wcat2);

  // qg' = -(q @ Wg[:,F:].T + bg) * log2e  (once, reused by both gates)
  kmm<6><<<dim3(ML / 64, F / 64), 256, 0, stream>>>(
      qbf, F, WgR, F, qg, F, F, bg, nullptr, nullptr, nullptr, 0, NEG_LOG2E);

  for (int layer = 0; layer < 2; ++layer) {
    const unsigned short* Wcat = layer ? Wcat2 : Wcat1;
    const float* bb = layer ? b2 : b1;

    // Acat right = per-relation means of Acat left
    kagg<<<BNn, 192, 0, stream>>>(offs, sorted, Acat, Acat + F);

    // parts[s] = Acat[:, s*768:(s+1)*768] @ Wcat[:, s*768:(s+1)*768].T  (split-K x4)
    kmm_pk<<<dim3(BNn / 64, F / 64, 4), 256, 0, stream>>>(
        Acat, 3072, Wcat, 3072, parts, F, PSTR);

    // hb = bf16(relu(sum parts + bias))
    kep_relu<<<(BNn * F) / 1024, 256, 0, stream>>>(parts, PSTR, bb, hb);

    // [hg' | zh] = hb @ [WgL | WqL].T ; left cols scaled by -log2e
    kmm<5><<<dim3(BNn / 64, 1536 / 64), 256, 0, stream>>>(
        hb, F, Wgq, F, hgz, 1536, F, nullptr, nullptr, nullptr, nullptr, 0, NEG_LOG2E);

    // qi (bf16) + tq (in place over hg)
    kqi<<<BNn / 2, 256, 0, stream>>>(hgz, q, qg, qib, npb, L);

    // z = zh + qi @ WqR.T + bq ; out = sig(z)*tq + (1-sig(z))*hb
    if (layer == 0) {
      kmm<3><<<dim3(BNn / 64, F / 64), 256, 0, stream>>>(
          qib, F, WqR, F, nullptr, 0, F, bq, hgz, hb, Acat, 3072, 0.f);
    } else {
      kmm<4><<<dim3(BNn / 64, F / 64), 256, 0, stream>>>(
          qib, F, WqR, F, out, F, F, bq, hgz, hb, nullptr, 0, 0.f);
    }
  }
}

// Round 6
// 335.012 us; speedup vs baseline: 3.1411x; 1.0091x over previous
//
#include <hip/hip_runtime.h>
#include <hip/hip_bf16.h>
#include <cstdint>
#include <cstddef>

#define F 768

typedef float f32x4 __attribute__((ext_vector_type(4)));
typedef short s16x8 __attribute__((ext_vector_type(8)));
typedef short s16x4 __attribute__((ext_vector_type(4)));

#define NEG_LOG2E (-1.4426950408889634f)

__device__ __forceinline__ float bf2f(unsigned short u) {
  union { unsigned int i; float f; } v; v.i = ((unsigned int)u) << 16; return v.f;
}
__device__ __forceinline__ unsigned short f2bf(float f) {
  union { float f; unsigned int i; } v; v.f = f;
  unsigned int r = v.i + 0x7FFF + ((v.i >> 16) & 1);  // RNE
  return (unsigned short)(r >> 16);
}

#if __has_builtin(__builtin_amdgcn_exp2f)
__device__ __forceinline__ float fexp2(float x) { return __builtin_amdgcn_exp2f(x); }
#else
__device__ __forceinline__ float fexp2(float x) { return exp2f(x); }
#endif
#if __has_builtin(__builtin_amdgcn_rcpf)
__device__ __forceinline__ float frcp(float x) { return __builtin_amdgcn_rcpf(x); }
#else
__device__ __forceinline__ float frcp(float x) { return 1.0f / x; }
#endif

__device__ __forceinline__ float ftanh(float x) {
  float t = fexp2(x * 2.8853900817779268f);
  float s = frcp(t + 1.0f);
  return fmaf(-2.0f, s, 1.0f);
}

__device__ __forceinline__ void gload16(const void* g, void* l) {
  __builtin_amdgcn_global_load_lds(
      (const __attribute__((address_space(1))) void*)g,
      (__attribute__((address_space(3))) void*)l, 16, 0, 0);
}

// ---------------- CSR build ----------------
__global__ void khist(const int* __restrict__ ei, int E, int* __restrict__ cnt) {
  int e = blockIdx.x * blockDim.x + threadIdx.x;
  if (e < E) atomicAdd(&cnt[ei[E + e]], 1);
}

__global__ void kscan(const int* __restrict__ cnt, int* __restrict__ offs, int n) {
  __shared__ int part[256];
  int t = threadIdx.x;
  const int per = n / 256;  // 8
  int local[8];
  int s = 0;
  for (int j = 0; j < per; ++j) { local[j] = cnt[t * per + j]; s += local[j]; }
  part[t] = s;
  __syncthreads();
  for (int d = 1; d < 256; d <<= 1) {
    int v = (t >= d) ? part[t - d] : 0;
    __syncthreads();
    part[t] += v;
    __syncthreads();
  }
  int run = (t == 0) ? 0 : part[t - 1];
  for (int j = 0; j < per; ++j) { offs[t * per + j] = run; run += local[j]; }
  if (t == 255) offs[n] = run;
}

__global__ void kscatter(const int* __restrict__ ei, const int* __restrict__ et, int E,
                         const int* __restrict__ offs, int* __restrict__ cur,
                         int* __restrict__ sorted) {
  int e = blockIdx.x * blockDim.x + threadIdx.x;
  if (e >= E) return;
  int dst = ei[E + e];
  int pos = offs[dst] + atomicAdd(&cur[dst], 1);
  sorted[pos] = ei[e] | (et[e] << 16);
}

// ---------------- prep: bf16 convert x (-> Acat, ld 3072) and q (-> qbf, ld 768) ----
__global__ void kcvt(const float* __restrict__ x, const float* __restrict__ q, int nx,
                     unsigned short* __restrict__ Acat, unsigned short* __restrict__ qbf) {
  const int r = blockIdx.x, c = threadIdx.x * 4;
  const float* srow;
  unsigned short* drow;
  if (r < nx) { srow = x + (size_t)r * F; drow = Acat + (size_t)r * 3072; }
  else        { srow = q + (size_t)(r - nx) * F; drow = qbf + (size_t)(r - nx) * F; }
  float4 v = *(const float4*)(srow + c);
  s16x4 o;
  o[0] = (short)f2bf(v.x); o[1] = (short)f2bf(v.y);
  o[2] = (short)f2bf(v.z); o[3] = (short)f2bf(v.w);
  *(s16x4*)(drow + c) = o;
}

// gate-weight prep: Wgq[1536][768] = rows of Wg[:, :F] then Wq[:, :F];
// WgR = Wg[:, F:]; WqR = Wq[:, F:]. grid 3072 x 192.
__global__ void kcvtw(const float* __restrict__ Wg, const float* __restrict__ Wq,
                      unsigned short* __restrict__ Wgq, unsigned short* __restrict__ WgR,
                      unsigned short* __restrict__ WqR) {
  const int b = blockIdx.x, c = threadIdx.x * 4;
  const float* srow;
  unsigned short* drow;
  int off;
  if (b < 1536) {
    srow = (b < 768) ? Wg + (size_t)b * 1536 : Wq + (size_t)(b - 768) * 1536;
    drow = Wgq + (size_t)b * 768;
    off = 0;
  } else if (b < 2304) {
    srow = Wg + (size_t)(b - 1536) * 1536;
    drow = WgR + (size_t)(b - 1536) * 768;
    off = 768;
  } else {
    srow = Wq + (size_t)(b - 2304) * 1536;
    drow = WqR + (size_t)(b - 2304) * 768;
    off = 768;
  }
  float4 v = *(const float4*)(srow + off + c);
  s16x4 o;
  o[0] = (short)f2bf(v.x); o[1] = (short)f2bf(v.y);
  o[2] = (short)f2bf(v.z); o[3] = (short)f2bf(v.w);
  *(s16x4*)(drow + c) = o;
}

// transpose-convert: Wcat_l[n][part*768 + k] = Wpart[k][n], grid (12,12,8)
__global__ void ktrans(const float* __restrict__ Wr1, const float* __restrict__ Wl1,
                       const float* __restrict__ Wr2, const float* __restrict__ Wl2,
                       unsigned short* __restrict__ Wcat1, unsigned short* __restrict__ Wcat2) {
  __shared__ float tile[64][65];
  const int z = blockIdx.z, layer = z >> 2, part = z & 3;
  const float* src = (part == 0) ? (layer ? Wr2 : Wr1)
                                 : ((layer ? Wl2 : Wl1) + (size_t)(part - 1) * F * F);
  unsigned short* dst = (layer ? Wcat2 : Wcat1) + part * F;
  const int kt = blockIdx.x * 64, nt = blockIdx.y * 64;
  const int t = threadIdx.x, c = t & 63, r4 = t >> 6;
#pragma unroll
  for (int it = 0; it < 16; ++it) {
    int kk = r4 + it * 4;
    tile[kk][c] = src[(size_t)(kt + kk) * F + nt + c];
  }
  __syncthreads();
#pragma unroll
  for (int it = 0; it < 16; ++it) {
    int rr = r4 + it * 4;
    dst[(size_t)(nt + rr) * 3072 + kt + c] = f2bf(tile[c][rr]);
  }
}

// ---------------- per-(dst,relation) mean; 192 thr, ushort4/lane, unroll 4 ----------
__global__ void kagg(const int* __restrict__ offs, const int* __restrict__ sorted,
                     const unsigned short* __restrict__ hin,   // Acat left, ld 3072
                     unsigned short* __restrict__ dst) {       // Acat + 768
  const int i = blockIdx.x, t = threadIdx.x;
  const int col = t * 4;
  float a0[4] = {}, a1[4] = {}, a2[4] = {};
  int c0 = 0, c1 = 0, c2 = 0;
  const int beg = offs[i], end = offs[i + 1];
  int e = beg;
  for (; e + 3 < end; e += 4) {
    int pk[4];
#pragma unroll
    for (int u = 0; u < 4; ++u) pk[u] = sorted[e + u];
    s16x4 w[4];
#pragma unroll
    for (int u = 0; u < 4; ++u)
      w[u] = *(const s16x4*)(hin + (size_t)(pk[u] & 0xFFFF) * 3072 + col);
#pragma unroll
    for (int u = 0; u < 4; ++u) {
      int r = pk[u] >> 16;
      float v[4];
#pragma unroll
      for (int j = 0; j < 4; ++j) v[j] = bf2f((unsigned short)w[u][j]);
      if (r == 0)      { c0++; for (int j = 0; j < 4; ++j) a0[j] += v[j]; }
      else if (r == 1) { c1++; for (int j = 0; j < 4; ++j) a1[j] += v[j]; }
      else             { c2++; for (int j = 0; j < 4; ++j) a2[j] += v[j]; }
    }
  }
  for (; e < end; ++e) {
    int p0 = sorted[e];
    s16x4 w0 = *(const s16x4*)(hin + (size_t)(p0 & 0xFFFF) * 3072 + col);
    int r0 = p0 >> 16;
    float v0[4];
#pragma unroll
    for (int j = 0; j < 4; ++j) v0[j] = bf2f((unsigned short)w0[j]);
    if (r0 == 0)      { c0++; for (int j = 0; j < 4; ++j) a0[j] += v0[j]; }
    else if (r0 == 1) { c1++; for (int j = 0; j < 4; ++j) a1[j] += v0[j]; }
    else              { c2++; for (int j = 0; j < 4; ++j) a2[j] += v0[j]; }
  }
  const float i0 = frcp((float)(c0 > 0 ? c0 : 1));
  const float i1 = frcp((float)(c1 > 0 ? c1 : 1));
  const float i2 = frcp((float)(c2 > 0 ? c2 : 1));
  unsigned short* d = dst + (size_t)i * 3072 + col;
  s16x4 o;
#pragma unroll
  for (int j = 0; j < 4; ++j) o[j] = (short)f2bf(a0[j] * i0);
  *(s16x4*)d = o;
#pragma unroll
  for (int j = 0; j < 4; ++j) o[j] = (short)f2bf(a1[j] * i1);
  *(s16x4*)(d + F) = o;
#pragma unroll
  for (int j = 0; j < 4; ++j) o[j] = (short)f2bf(a2[j] * i2);
  *(s16x4*)(d + 2 * F) = o;
}

// ---------------- bf16 MFMA GEMM, 64x64 tile, BK=64, dbuf LDS, fused epilogues ----
// EPI: 3 gate-mix -> bf16 C2 | 4 gate-mix -> f32 C
//      6 (v+bias)*escale -> f32                       (qg prep)
//      7 [hg|zh] GEMM with FUSED qi/tanh epilogue:
//        bn>=768: store zh -> C(hgz)
//        bn< 768: qi = sum_l sig*q -> bf16 C2(qib); tanh(qi) -> C(hgz left)
//        (bias = pre-scaled qg', aux1 = raw q f32)
template <int EPI>
__launch_bounds__(256)
__global__ void kmm(const unsigned short* __restrict__ A, int lda,
                    const unsigned short* __restrict__ B, int ldb,
                    float* __restrict__ C, int ldc, int K,
                    const float* __restrict__ bias,
                    const float* __restrict__ aux1,          // EPI3/4: hgz (tq|zh); EPI7: raw q
                    const unsigned short* __restrict__ aux2, // hb bf16, ld 768
                    unsigned short* __restrict__ C2, int ldc2,
                    float escale, int Lq) {
  __shared__ unsigned short Asb[2][64 * 64];
  __shared__ unsigned short Bsb[2][64 * 64];
  const int t = threadIdx.x;
  const int lane = t & 63, wid = t >> 6;
  const int wr = wid >> 1, wc = wid & 1;
  const int bm = blockIdx.x * 64, bn = blockIdx.y * 64;

  const int srow = lane >> 3, schunk = lane & 7;
  const int kxor = ((schunk ^ srow) << 3);
  const int rowA = wid * 16 + srow;
  const unsigned short* Ap = A + (size_t)(bm + rowA) * lda + kxor;
  const unsigned short* Bp = B + (size_t)(bn + rowA) * ldb + kxor;
  const int lbase = wid * 16 * 64;

  const int rA0 = wr * 32 + (lane & 15);
  const int rB0 = wc * 32 + (lane & 15);
  const int l7 = lane & 7, lq = lane >> 4;
  const int s8_0 = (((0 * 4 + lq) ^ l7) << 3);
  const int s8_1 = (((1 * 4 + lq) ^ l7) << 3);

  f32x4 acc[2][2] = {};

  auto stage = [&](int cb, int k0) {
#pragma unroll
    for (int j = 0; j < 2; ++j) {
      gload16(Ap + (size_t)j * 8 * lda + k0, &Asb[cb][lbase + j * 512]);
      gload16(Bp + (size_t)j * 8 * ldb + k0, &Bsb[cb][lbase + j * 512]);
    }
  };

  stage(0, 0);
  __syncthreads();
  int cur = 0;
  for (int k0 = 0; k0 < K; k0 += 64) {
    if (k0 + 64 < K) stage(cur ^ 1, k0 + 64);
    const unsigned short* As = Asb[cur];
    const unsigned short* Bs = Bsb[cur];
#pragma unroll
    for (int ks = 0; ks < 2; ++ks) {
      const int s8 = ks ? s8_1 : s8_0;
      s16x8 af[2], bf[2];
#pragma unroll
      for (int i = 0; i < 2; ++i)
        af[i] = *(const s16x8*)(As + (rA0 + i * 16) * 64 + s8);
#pragma unroll
      for (int n = 0; n < 2; ++n)
        bf[n] = *(const s16x8*)(Bs + (rB0 + n * 16) * 64 + s8);
#pragma unroll
      for (int i = 0; i < 2; ++i)
#pragma unroll
        for (int n = 0; n < 2; ++n)
          acc[i][n] = __builtin_amdgcn_mfma_f32_16x16x32_bf16(af[i], bf[n], acc[i][n], 0, 0, 0);
    }
    __syncthreads();
    cur ^= 1;
  }

  if (EPI == 7 && bn < 768) {
    // fused qi epilogue: qi[row,col] = sum_l sig(hg+qg')·q ; write qib + tanh->hgz
    float hgp[2][2][4], qacc[2][2][4];
#pragma unroll
    for (int i = 0; i < 2; ++i)
#pragma unroll
      for (int n = 0; n < 2; ++n)
#pragma unroll
        for (int j = 0; j < 4; ++j) {
          hgp[i][n][j] = acc[i][n][j] * NEG_LOG2E;
          qacc[i][n][j] = 0.0f;
        }
    const int b = bm >> 8;
    const int col0 = bn + wc * 32 + (lane & 15);
    const float* qb = aux1 + (size_t)b * Lq * F;   // raw q
    const float* qgb = bias + (size_t)b * Lq * F;  // pre-scaled qg'
#pragma unroll 2
    for (int l = 0; l < Lq; ++l) {
      const float qg0 = qgb[(size_t)l * F + col0];
      const float qg1 = qgb[(size_t)l * F + col0 + 16];
      const float q0 = qb[(size_t)l * F + col0];
      const float q1 = qb[(size_t)l * F + col0 + 16];
#pragma unroll
      for (int i = 0; i < 2; ++i)
#pragma unroll
        for (int j = 0; j < 4; ++j) {
          qacc[i][0][j] = fmaf(frcp(1.0f + fexp2(hgp[i][0][j] + qg0)), q0, qacc[i][0][j]);
          qacc[i][1][j] = fmaf(frcp(1.0f + fexp2(hgp[i][1][j] + qg1)), q1, qacc[i][1][j]);
        }
    }
#pragma unroll
    for (int i = 0; i < 2; ++i)
#pragma unroll
      for (int n = 0; n < 2; ++n)
#pragma unroll
        for (int j = 0; j < 4; ++j) {
          const int row = bm + wr * 32 + i * 16 + (lane >> 4) * 4 + j;
          const int col = col0 + n * 16;
          C2[(size_t)row * 768 + col] = f2bf(qacc[i][n][j]);   // qib
          C[(size_t)row * 1536 + col] = ftanh(qacc[i][n][j]);  // tq half of hgz
        }
    return;
  }

#pragma unroll
  for (int i = 0; i < 2; ++i)
#pragma unroll
    for (int n = 0; n < 2; ++n)
#pragma unroll
      for (int j = 0; j < 4; ++j) {
        const int row = bm + wr * 32 + i * 16 + (lane >> 4) * 4 + j;
        const int col = bn + wc * 32 + n * 16 + (lane & 15);
        float v = acc[i][n][j];
        if (EPI == 3 || EPI == 4) {
          float zh = aux1[(size_t)row * 1536 + 768 + col];
          float z = v + bias[col] + zh;
          float al = frcp(1.0f + fexp2(z * NEG_LOG2E));
          float tq = aux1[(size_t)row * 1536 + col];
          float hv = bf2f(aux2[(size_t)row * 768 + col]);
          float o = al * tq + (1.0f - al) * hv;
          if (EPI == 3) C2[(size_t)row * ldc2 + col] = f2bf(o);
          else          C[(size_t)row * ldc + col] = o;
        } else if (EPI == 6) {
          C[(size_t)row * ldc + col] = (v + bias[col]) * escale;
        } else {  // EPI 7, zh half
          C[(size_t)row * ldc + col] = v;
        }
      }
}

// split-K GEMM -> f32 partials. grid (M/64, N/64, S)
__launch_bounds__(256)
__global__ void kmm_pk(const unsigned short* __restrict__ A, int lda,
                       const unsigned short* __restrict__ B, int ldb,
                       float* __restrict__ P, int Ksplit, int pstride) {
  __shared__ unsigned short Asb[2][64 * 64];
  __shared__ unsigned short Bsb[2][64 * 64];
  const int t = threadIdx.x;
  const int lane = t & 63, wid = t >> 6;
  const int wr = wid >> 1, wc = wid & 1;
  const int bm = blockIdx.x * 64, bn = blockIdx.y * 64;
  const int kbase = blockIdx.z * Ksplit;
  float* Cp = P + (size_t)blockIdx.z * pstride;

  const int srow = lane >> 3, schunk = lane & 7;
  const int kxor = ((schunk ^ srow) << 3);
  const int rowA = wid * 16 + srow;
  const unsigned short* Ap = A + (size_t)(bm + rowA) * lda + kxor + kbase;
  const unsigned short* Bp = B + (size_t)(bn + rowA) * ldb + kxor + kbase;
  const int lbase = wid * 16 * 64;

  const int rA0 = wr * 32 + (lane & 15);
  const int rB0 = wc * 32 + (lane & 15);
  const int l7 = lane & 7, lq = lane >> 4;
  const int s8_0 = (((0 * 4 + lq) ^ l7) << 3);
  const int s8_1 = (((1 * 4 + lq) ^ l7) << 3);

  f32x4 acc[2][2] = {};

  auto stage = [&](int cb, int k0) {
#pragma unroll
    for (int j = 0; j < 2; ++j) {
      gload16(Ap + (size_t)j * 8 * lda + k0, &Asb[cb][lbase + j * 512]);
      gload16(Bp + (size_t)j * 8 * ldb + k0, &Bsb[cb][lbase + j * 512]);
    }
  };

  stage(0, 0);
  __syncthreads();
  int cur = 0;
  for (int k0 = 0; k0 < Ksplit; k0 += 64) {
    if (k0 + 64 < Ksplit) stage(cur ^ 1, k0 + 64);
    const unsigned short* As = Asb[cur];
    const unsigned short* Bs = Bsb[cur];
#pragma unroll
    for (int ks = 0; ks < 2; ++ks) {
      const int s8 = ks ? s8_1 : s8_0;
      s16x8 af[2], bf[2];
#pragma unroll
      for (int i = 0; i < 2; ++i)
        af[i] = *(const s16x8*)(As + (rA0 + i * 16) * 64 + s8);
#pragma unroll
      for (int n = 0; n < 2; ++n)
        bf[n] = *(const s16x8*)(Bs + (rB0 + n * 16) * 64 + s8);
#pragma unroll
      for (int i = 0; i < 2; ++i)
#pragma unroll
        for (int n = 0; n < 2; ++n)
          acc[i][n] = __builtin_amdgcn_mfma_f32_16x16x32_bf16(af[i], bf[n], acc[i][n], 0, 0, 0);
    }
    __syncthreads();
    cur ^= 1;
  }

#pragma unroll
  for (int i = 0; i < 2; ++i)
#pragma unroll
    for (int n = 0; n < 2; ++n)
#pragma unroll
      for (int j = 0; j < 4; ++j) {
        const int row = bm + wr * 32 + i * 16 + (lane >> 4) * 4 + j;
        const int col = bn + wc * 32 + n * 16 + (lane & 15);
        Cp[(size_t)row * F + col] = acc[i][n][j];
      }
}

// reduce 4 partials + bias -> relu -> bf16 hb. grid 1536 x 256, float4/thr.
__global__ void kep_relu(const float* __restrict__ P, int pstride,
                         const float* __restrict__ bias,
                         unsigned short* __restrict__ hb) {
  const int idx = (blockIdx.x * 256 + threadIdx.x) * 4;
  const int col = idx - (idx / F) * F;
  float4 s = *(const float4*)(P + idx);
  const float4 s1 = *(const float4*)(P + pstride + idx);
  const float4 s2 = *(const float4*)(P + 2 * (size_t)pstride + idx);
  const float4 s3 = *(const float4*)(P + 3 * (size_t)pstride + idx);
  const float4 bv = *(const float4*)(bias + col);
  s.x = fmaxf(s.x + s1.x + s2.x + s3.x + bv.x, 0.0f);
  s.y = fmaxf(s.y + s1.y + s2.y + s3.y + bv.y, 0.0f);
  s.z = fmaxf(s.z + s1.z + s2.z + s3.z + bv.z, 0.0f);
  s.w = fmaxf(s.w + s1.w + s2.w + s3.w + bv.w, 0.0f);
  s16x4 o;
  o[0] = (short)f2bf(s.x); o[1] = (short)f2bf(s.y);
  o[2] = (short)f2bf(s.z); o[3] = (short)f2bf(s.w);
  *(s16x4*)(hb + idx) = o;
}

// ---------------- launch ----------------
extern "C" void kernel_launch(void* const* d_in, const int* in_sizes, int n_in,
                              void* d_out, int out_size, void* d_ws, size_t ws_size,
                              hipStream_t stream) {
  const float* x = (const float*)d_in[0];
  const int* ei = (const int*)d_in[1];
  const int* et = (const int*)d_in[2];
  const float* q = (const float*)d_in[3];
  const float* Wrel1 = (const float*)d_in[4];
  const float* Wroot1 = (const float*)d_in[5];
  const float* b1 = (const float*)d_in[6];
  const float* Wrel2 = (const float*)d_in[7];
  const float* Wroot2 = (const float*)d_in[8];
  const float* b2 = (const float*)d_in[9];
  const float* Wg = (const float*)d_in[10];
  const float* bg = (const float*)d_in[11];
  const float* Wq = (const float*)d_in[12];
  const float* bq = (const float*)d_in[13];

  const int BNn = in_sizes[0] / F;       // 2048
  const int E = in_sizes[1] / 2;         // 65536
  const int L = 64;
  const int Bq = in_sizes[3] / (L * F);  // 8
  const int ML = Bq * L;                 // 512
  const int PSTR = BNn * F;              // partial stride (elements)
  float* out = (float*)d_out;

  char* p = (char*)d_ws;
  auto alloc = [&](size_t bytes) {
    void* r = (void*)p;
    p += (bytes + 255) & ~(size_t)255;
    return r;
  };
  int* cntcur = (int*)alloc((size_t)2 * BNn * 4);  // cnt | cur, one memset
  int* cnt = cntcur;
  int* cur = cntcur + BNn;
  int* offs = (int*)alloc((size_t)(BNn + 1) * 4);
  int* sorted = (int*)alloc((size_t)E * 4);
  unsigned short* Acat = (unsigned short*)alloc((size_t)BNn * 3072 * 2);
  unsigned short* Wcat1 = (unsigned short*)alloc((size_t)F * 3072 * 2);
  unsigned short* Wcat2 = (unsigned short*)alloc((size_t)F * 3072 * 2);
  unsigned short* Wgq = (unsigned short*)alloc((size_t)1536 * F * 2);
  unsigned short* WgR = (unsigned short*)alloc((size_t)F * F * 2);
  unsigned short* WqR = (unsigned short*)alloc((size_t)F * F * 2);
  unsigned short* qbf = (unsigned short*)alloc((size_t)ML * F * 2);
  float* qg = (float*)alloc((size_t)ML * F * 4);
  unsigned short* hb = (unsigned short*)alloc((size_t)BNn * F * 2);
  float* hgz = (float*)alloc((size_t)BNn * 1536 * 4);   // [tq | zh]
  unsigned short* qib = (unsigned short*)alloc((size_t)BNn * F * 2);
  float* parts = (float*)alloc((size_t)4 * PSTR * 4);

  hipMemsetAsync(cntcur, 0, (size_t)2 * BNn * 4, stream);
  khist<<<(E + 255) / 256, 256, 0, stream>>>(ei, E, cnt);
  kscan<<<1, 256, 0, stream>>>(cnt, offs, BNn);
  kscatter<<<(E + 255) / 256, 256, 0, stream>>>(ei, et, E, offs, cur, sorted);

  kcvt<<<BNn + ML, 192, 0, stream>>>(x, q, BNn, Acat, qbf);
  kcvtw<<<3072, 192, 0, stream>>>(Wg, Wq, Wgq, WgR, WqR);
  ktrans<<<dim3(12, 12, 8), 256, 0, stream>>>(Wroot1, Wrel1, Wroot2, Wrel2, Wcat1, Wcat2);

  // qg' = -(q @ Wg[:,F:].T + bg) * log2e  (once, reused by both gates)
  kmm<6><<<dim3(ML / 64, F / 64), 256, 0, stream>>>(
      qbf, F, WgR, F, qg, F, F, bg, nullptr, nullptr, nullptr, 0, NEG_LOG2E, L);

  for (int layer = 0; layer < 2; ++layer) {
    const unsigned short* Wcat = layer ? Wcat2 : Wcat1;
    const float* bb = layer ? b2 : b1;

    // Acat right = per-relation means of Acat left
    kagg<<<BNn, 192, 0, stream>>>(offs, sorted, Acat, Acat + F);

    // parts[s] = Acat[:, s*768:(s+1)*768] @ Wcat[:, s*768:(s+1)*768].T  (split-K x4)
    kmm_pk<<<dim3(BNn / 64, F / 64, 4), 256, 0, stream>>>(
        Acat, 3072, Wcat, 3072, parts, F, PSTR);

    // hb = bf16(relu(sum parts + bias))
    kep_relu<<<(BNn * F) / 1024, 256, 0, stream>>>(parts, PSTR, bb, hb);

    // [hg | zh] = hb @ [WgL | WqL].T with FUSED qi/tanh epilogue on the hg half
    kmm<7><<<dim3(BNn / 64, 1536 / 64), 256, 0, stream>>>(
        hb, F, Wgq, F, hgz, 1536, F, qg, q, nullptr, qib, F, 0.f, L);

    // z = zh + qi @ WqR.T + bq ; out = sig(z)*tq + (1-sig(z))*hb
    if (layer == 0) {
      kmm<3><<<dim3(BNn / 64, F / 64), 256, 0, stream>>>(
          qib, F, WqR, F, nullptr, 0, F, bq, hgz, hb, Acat, 3072, 0.f, L);
    } else {
      kmm<4><<<dim3(BNn / 64, F / 64), 256, 0, stream>>>(
          qib, F, WqR, F, out, F, F, bq, hgz, hb, nullptr, 0, 0.f, L);
    }
  }
}

// Round 7
// 318.021 us; speedup vs baseline: 3.3089x; 1.0534x over previous
//
#include <hip/hip_runtime.h>
#include <hip/hip_bf16.h>
#include <cstdint>
#include <cstddef>

#define F 768

typedef float f32x4 __attribute__((ext_vector_type(4)));
typedef short s16x8 __attribute__((ext_vector_type(8)));
typedef short s16x4 __attribute__((ext_vector_type(4)));

#define NEG_LOG2E (-1.4426950408889634f)

__device__ __forceinline__ float bf2f(unsigned short u) {
  union { unsigned int i; float f; } v; v.i = ((unsigned int)u) << 16; return v.f;
}
__device__ __forceinline__ unsigned short f2bf(float f) {
  union { float f; unsigned int i; } v; v.f = f;
  unsigned int r = v.i + 0x7FFF + ((v.i >> 16) & 1);  // RNE
  return (unsigned short)(r >> 16);
}

#if __has_builtin(__builtin_amdgcn_exp2f)
__device__ __forceinline__ float fexp2(float x) { return __builtin_amdgcn_exp2f(x); }
#else
__device__ __forceinline__ float fexp2(float x) { return exp2f(x); }
#endif
#if __has_builtin(__builtin_amdgcn_rcpf)
__device__ __forceinline__ float frcp(float x) { return __builtin_amdgcn_rcpf(x); }
#else
__device__ __forceinline__ float frcp(float x) { return 1.0f / x; }
#endif

__device__ __forceinline__ float ftanh(float x) {
  float t = fexp2(x * 2.8853900817779268f);
  float s = frcp(t + 1.0f);
  return fmaf(-2.0f, s, 1.0f);
}

__device__ __forceinline__ void gload16(const void* g, void* l) {
  __builtin_amdgcn_global_load_lds(
      (const __attribute__((address_space(1))) void*)g,
      (__attribute__((address_space(3))) void*)l, 16, 0, 0);
}

// ---------------- CSR build ----------------
__global__ void khist(const int* __restrict__ ei, int E, int* __restrict__ cnt) {
  int e = blockIdx.x * blockDim.x + threadIdx.x;
  if (e < E) atomicAdd(&cnt[ei[E + e]], 1);
}

__global__ void kscan(const int* __restrict__ cnt, int* __restrict__ offs, int n) {
  __shared__ int part[256];
  int t = threadIdx.x;
  const int per = n / 256;  // 8
  int local[8];
  int s = 0;
  for (int j = 0; j < per; ++j) { local[j] = cnt[t * per + j]; s += local[j]; }
  part[t] = s;
  __syncthreads();
  for (int d = 1; d < 256; d <<= 1) {
    int v = (t >= d) ? part[t - d] : 0;
    __syncthreads();
    part[t] += v;
    __syncthreads();
  }
  int run = (t == 0) ? 0 : part[t - 1];
  for (int j = 0; j < per; ++j) { offs[t * per + j] = run; run += local[j]; }
  if (t == 255) offs[n] = run;
}

__global__ void kscatter(const int* __restrict__ ei, const int* __restrict__ et, int E,
                         const int* __restrict__ offs, int* __restrict__ cur,
                         int* __restrict__ sorted) {
  int e = blockIdx.x * blockDim.x + threadIdx.x;
  if (e >= E) return;
  int dst = ei[E + e];
  int pos = offs[dst] + atomicAdd(&cur[dst], 1);
  sorted[pos] = ei[e] | (et[e] << 16);
}

// ---------------- prep: bf16 convert x (-> Acat, ld 3072) and q (-> qbf, ld 768) ----
__global__ void kcvt(const float* __restrict__ x, const float* __restrict__ q, int nx,
                     unsigned short* __restrict__ Acat, unsigned short* __restrict__ qbf) {
  const int r = blockIdx.x, c = threadIdx.x * 4;
  const float* srow;
  unsigned short* drow;
  if (r < nx) { srow = x + (size_t)r * F; drow = Acat + (size_t)r * 3072; }
  else        { srow = q + (size_t)(r - nx) * F; drow = qbf + (size_t)(r - nx) * F; }
  float4 v = *(const float4*)(srow + c);
  s16x4 o;
  o[0] = (short)f2bf(v.x); o[1] = (short)f2bf(v.y);
  o[2] = (short)f2bf(v.z); o[3] = (short)f2bf(v.w);
  *(s16x4*)(drow + c) = o;
}

// gate-weight prep: Wgq[1536][768] = rows of Wg[:, :F] then Wq[:, :F];
// WgR = Wg[:, F:]; WqR = Wq[:, F:]. grid 3072 x 192.
__global__ void kcvtw(const float* __restrict__ Wg, const float* __restrict__ Wq,
                      unsigned short* __restrict__ Wgq, unsigned short* __restrict__ WgR,
                      unsigned short* __restrict__ WqR) {
  const int b = blockIdx.x, c = threadIdx.x * 4;
  const float* srow;
  unsigned short* drow;
  int off;
  if (b < 1536) {
    srow = (b < 768) ? Wg + (size_t)b * 1536 : Wq + (size_t)(b - 768) * 1536;
    drow = Wgq + (size_t)b * 768;
    off = 0;
  } else if (b < 2304) {
    srow = Wg + (size_t)(b - 1536) * 1536;
    drow = WgR + (size_t)(b - 1536) * 768;
    off = 768;
  } else {
    srow = Wq + (size_t)(b - 2304) * 1536;
    drow = WqR + (size_t)(b - 2304) * 768;
    off = 768;
  }
  float4 v = *(const float4*)(srow + off + c);
  s16x4 o;
  o[0] = (short)f2bf(v.x); o[1] = (short)f2bf(v.y);
  o[2] = (short)f2bf(v.z); o[3] = (short)f2bf(v.w);
  *(s16x4*)(drow + c) = o;
}

// transpose-convert: Wcat_l[n][part*768 + k] = Wpart[k][n], grid (12,12,8)
__global__ void ktrans(const float* __restrict__ Wr1, const float* __restrict__ Wl1,
                       const float* __restrict__ Wr2, const float* __restrict__ Wl2,
                       unsigned short* __restrict__ Wcat1, unsigned short* __restrict__ Wcat2) {
  __shared__ float tile[64][65];
  const int z = blockIdx.z, layer = z >> 2, part = z & 3;
  const float* src = (part == 0) ? (layer ? Wr2 : Wr1)
                                 : ((layer ? Wl2 : Wl1) + (size_t)(part - 1) * F * F);
  unsigned short* dst = (layer ? Wcat2 : Wcat1) + part * F;
  const int kt = blockIdx.x * 64, nt = blockIdx.y * 64;
  const int t = threadIdx.x, c = t & 63, r4 = t >> 6;
#pragma unroll
  for (int it = 0; it < 16; ++it) {
    int kk = r4 + it * 4;
    tile[kk][c] = src[(size_t)(kt + kk) * F + nt + c];
  }
  __syncthreads();
#pragma unroll
  for (int it = 0; it < 16; ++it) {
    int rr = r4 + it * 4;
    dst[(size_t)(nt + rr) * 3072 + kt + c] = f2bf(tile[c][rr]);
  }
}

// ---------------- per-(dst,relation) mean; 192 thr, ushort4/lane, unroll 4 ----------
__global__ void kagg(const int* __restrict__ offs, const int* __restrict__ sorted,
                     const unsigned short* __restrict__ hin,   // Acat left, ld 3072
                     unsigned short* __restrict__ dst) {       // Acat + 768
  const int i = blockIdx.x, t = threadIdx.x;
  const int col = t * 4;
  float a0[4] = {}, a1[4] = {}, a2[4] = {};
  int c0 = 0, c1 = 0, c2 = 0;
  const int beg = offs[i], end = offs[i + 1];
  int e = beg;
  for (; e + 3 < end; e += 4) {
    int pk[4];
#pragma unroll
    for (int u = 0; u < 4; ++u) pk[u] = sorted[e + u];
    s16x4 w[4];
#pragma unroll
    for (int u = 0; u < 4; ++u)
      w[u] = *(const s16x4*)(hin + (size_t)(pk[u] & 0xFFFF) * 3072 + col);
#pragma unroll
    for (int u = 0; u < 4; ++u) {
      int r = pk[u] >> 16;
      float v[4];
#pragma unroll
      for (int j = 0; j < 4; ++j) v[j] = bf2f((unsigned short)w[u][j]);
      if (r == 0)      { c0++; for (int j = 0; j < 4; ++j) a0[j] += v[j]; }
      else if (r == 1) { c1++; for (int j = 0; j < 4; ++j) a1[j] += v[j]; }
      else             { c2++; for (int j = 0; j < 4; ++j) a2[j] += v[j]; }
    }
  }
  for (; e < end; ++e) {
    int p0 = sorted[e];
    s16x4 w0 = *(const s16x4*)(hin + (size_t)(p0 & 0xFFFF) * 3072 + col);
    int r0 = p0 >> 16;
    float v0[4];
#pragma unroll
    for (int j = 0; j < 4; ++j) v0[j] = bf2f((unsigned short)w0[j]);
    if (r0 == 0)      { c0++; for (int j = 0; j < 4; ++j) a0[j] += v0[j]; }
    else if (r0 == 1) { c1++; for (int j = 0; j < 4; ++j) a1[j] += v0[j]; }
    else              { c2++; for (int j = 0; j < 4; ++j) a2[j] += v0[j]; }
  }
  const float i0 = frcp((float)(c0 > 0 ? c0 : 1));
  const float i1 = frcp((float)(c1 > 0 ? c1 : 1));
  const float i2 = frcp((float)(c2 > 0 ? c2 : 1));
  unsigned short* d = dst + (size_t)i * 3072 + col;
  s16x4 o;
#pragma unroll
  for (int j = 0; j < 4; ++j) o[j] = (short)f2bf(a0[j] * i0);
  *(s16x4*)d = o;
#pragma unroll
  for (int j = 0; j < 4; ++j) o[j] = (short)f2bf(a1[j] * i1);
  *(s16x4*)(d + F) = o;
#pragma unroll
  for (int j = 0; j < 4; ++j) o[j] = (short)f2bf(a2[j] * i2);
  *(s16x4*)(d + 2 * F) = o;
}

// ---------------- bf16 MFMA GEMM, 64x64 tile, BK=64, 512 thr / 8 waves ----------
// Wave grid 2(M)x4(N): wave owns 32x16 -> 8 acc elements/thread (2 frags).
// EPI: 3 gate-mix -> bf16 C2 | 4 gate-mix -> f32 C
//      6 (v+bias)*escale -> f32                       (qg prep)
//      7 [hg|zh] with FUSED qi/tanh epilogue on bn<768 half
template <int EPI>
__launch_bounds__(512)
__global__ void kmm(const unsigned short* __restrict__ A, int lda,
                    const unsigned short* __restrict__ B, int ldb,
                    float* __restrict__ C, int ldc, int K,
                    const float* __restrict__ bias,
                    const float* __restrict__ aux1,          // EPI3/4: hgz (tq|zh); EPI7: raw q
                    const unsigned short* __restrict__ aux2, // hb bf16, ld 768
                    unsigned short* __restrict__ C2, int ldc2,
                    float escale, int Lq) {
  __shared__ unsigned short Asb[2][64 * 64];
  __shared__ unsigned short Bsb[2][64 * 64];
  const int t = threadIdx.x;
  const int lane = t & 63, wid = t >> 6;     // 8 waves
  const int wr = wid >> 2, wc = wid & 3;     // 2 x 4
  const int bm = blockIdx.x * 64, bn = blockIdx.y * 64;

  // staging: one 16B gload per thread per matrix per K-step
  const int srow = t >> 3, schunk = t & 7;
  const int kxor = ((schunk ^ (srow & 7)) << 3);
  const unsigned short* Ap = A + (size_t)(bm + srow) * lda + kxor;
  const unsigned short* Bp = B + (size_t)(bn + srow) * ldb + kxor;

  // fragment-read geometry (swizzled to match)
  const int rA0 = wr * 32 + (lane & 15);
  const int rB0 = wc * 16 + (lane & 15);
  const int l7 = lane & 7, lq = lane >> 4;
  const int s8_0 = (((0 * 4 + lq) ^ l7) << 3);
  const int s8_1 = (((1 * 4 + lq) ^ l7) << 3);

  f32x4 acc[2] = {};

  auto stage = [&](int cb, int k0) {
    gload16(Ap + k0, &Asb[cb][t * 8]);
    gload16(Bp + k0, &Bsb[cb][t * 8]);
  };

  stage(0, 0);
  __syncthreads();
  int cur = 0;
  for (int k0 = 0; k0 < K; k0 += 64) {
    if (k0 + 64 < K) stage(cur ^ 1, k0 + 64);
    const unsigned short* As = Asb[cur];
    const unsigned short* Bs = Bsb[cur];
#pragma unroll
    for (int ks = 0; ks < 2; ++ks) {
      const int s8 = ks ? s8_1 : s8_0;
      s16x8 af[2], bf;
#pragma unroll
      for (int i = 0; i < 2; ++i)
        af[i] = *(const s16x8*)(As + (rA0 + i * 16) * 64 + s8);
      bf = *(const s16x8*)(Bs + rB0 * 64 + s8);
#pragma unroll
      for (int i = 0; i < 2; ++i)
        acc[i] = __builtin_amdgcn_mfma_f32_16x16x32_bf16(af[i], bf, acc[i], 0, 0, 0);
    }
    __syncthreads();
    cur ^= 1;
  }

  const int colw = bn + wc * 16 + (lane & 15);

  if (EPI == 7 && bn < 768) {
    // fused qi epilogue: qi[row,col] = sum_l sig(hg+qg')·q ; write qib + tanh->hgz
    float hgp[2][4], qacc[2][4];
#pragma unroll
    for (int i = 0; i < 2; ++i)
#pragma unroll
      for (int j = 0; j < 4; ++j) {
        hgp[i][j] = acc[i][j] * NEG_LOG2E;
        qacc[i][j] = 0.0f;
      }
    const int b = bm >> 8;
    const float* qb = aux1 + (size_t)b * Lq * F;   // raw q
    const float* qgb = bias + (size_t)b * Lq * F;  // pre-scaled qg'
#pragma unroll 4
    for (int l = 0; l < Lq; ++l) {
      const float qg0 = qgb[(size_t)l * F + colw];
      const float q0 = qb[(size_t)l * F + colw];
#pragma unroll
      for (int i = 0; i < 2; ++i)
#pragma unroll
        for (int j = 0; j < 4; ++j)
          qacc[i][j] = fmaf(frcp(1.0f + fexp2(hgp[i][j] + qg0)), q0, qacc[i][j]);
    }
#pragma unroll
    for (int i = 0; i < 2; ++i)
#pragma unroll
      for (int j = 0; j < 4; ++j) {
        const int row = bm + wr * 32 + i * 16 + (lane >> 4) * 4 + j;
        C2[(size_t)row * 768 + colw] = f2bf(qacc[i][j]);   // qib
        C[(size_t)row * 1536 + colw] = ftanh(qacc[i][j]);  // tq half of hgz
      }
    return;
  }

#pragma unroll
  for (int i = 0; i < 2; ++i)
#pragma unroll
    for (int j = 0; j < 4; ++j) {
      const int row = bm + wr * 32 + i * 16 + (lane >> 4) * 4 + j;
      const int col = colw;
      float v = acc[i][j];
      if (EPI == 3 || EPI == 4) {
        float zh = aux1[(size_t)row * 1536 + 768 + col];
        float z = v + bias[col] + zh;
        float al = frcp(1.0f + fexp2(z * NEG_LOG2E));
        float tq = aux1[(size_t)row * 1536 + col];
        float hv = bf2f(aux2[(size_t)row * 768 + col]);
        float o = al * tq + (1.0f - al) * hv;
        if (EPI == 3) C2[(size_t)row * ldc2 + col] = f2bf(o);
        else          C[(size_t)row * ldc + col] = o;
      } else if (EPI == 6) {
        C[(size_t)row * ldc + col] = (v + bias[col]) * escale;
      } else {  // EPI 7, zh half
        C[(size_t)row * ldc + col] = v;
      }
    }
}

// split-K GEMM -> f32 partials. grid (M/64, N/64, S), 512 thr / 8 waves
__launch_bounds__(512)
__global__ void kmm_pk(const unsigned short* __restrict__ A, int lda,
                       const unsigned short* __restrict__ B, int ldb,
                       float* __restrict__ P, int Ksplit, int pstride) {
  __shared__ unsigned short Asb[2][64 * 64];
  __shared__ unsigned short Bsb[2][64 * 64];
  const int t = threadIdx.x;
  const int lane = t & 63, wid = t >> 6;
  const int wr = wid >> 2, wc = wid & 3;
  const int bm = blockIdx.x * 64, bn = blockIdx.y * 64;
  const int kbase = blockIdx.z * Ksplit;
  float* Cp = P + (size_t)blockIdx.z * pstride;

  const int srow = t >> 3, schunk = t & 7;
  const int kxor = ((schunk ^ (srow & 7)) << 3);
  const unsigned short* Ap = A + (size_t)(bm + srow) * lda + kxor + kbase;
  const unsigned short* Bp = B + (size_t)(bn + srow) * ldb + kxor + kbase;

  const int rA0 = wr * 32 + (lane & 15);
  const int rB0 = wc * 16 + (lane & 15);
  const int l7 = lane & 7, lq = lane >> 4;
  const int s8_0 = (((0 * 4 + lq) ^ l7) << 3);
  const int s8_1 = (((1 * 4 + lq) ^ l7) << 3);

  f32x4 acc[2] = {};

  auto stage = [&](int cb, int k0) {
    gload16(Ap + k0, &Asb[cb][t * 8]);
    gload16(Bp + k0, &Bsb[cb][t * 8]);
  };

  stage(0, 0);
  __syncthreads();
  int cur = 0;
  for (int k0 = 0; k0 < Ksplit; k0 += 64) {
    if (k0 + 64 < Ksplit) stage(cur ^ 1, k0 + 64);
    const unsigned short* As = Asb[cur];
    const unsigned short* Bs = Bsb[cur];
#pragma unroll
    for (int ks = 0; ks < 2; ++ks) {
      const int s8 = ks ? s8_1 : s8_0;
      s16x8 af[2], bf;
#pragma unroll
      for (int i = 0; i < 2; ++i)
        af[i] = *(const s16x8*)(As + (rA0 + i * 16) * 64 + s8);
      bf = *(const s16x8*)(Bs + rB0 * 64 + s8);
#pragma unroll
      for (int i = 0; i < 2; ++i)
        acc[i] = __builtin_amdgcn_mfma_f32_16x16x32_bf16(af[i], bf, acc[i], 0, 0, 0);
    }
    __syncthreads();
    cur ^= 1;
  }

  const int col = bn + wc * 16 + (lane & 15);
#pragma unroll
  for (int i = 0; i < 2; ++i)
#pragma unroll
    for (int j = 0; j < 4; ++j) {
      const int row = bm + wr * 32 + i * 16 + (lane >> 4) * 4 + j;
      Cp[(size_t)row * F + col] = acc[i][j];
    }
}

// reduce 4 partials + bias -> relu -> bf16 hb. grid 1536 x 256, float4/thr.
__global__ void kep_relu(const float* __restrict__ P, int pstride,
                         const float* __restrict__ bias,
                         unsigned short* __restrict__ hb) {
  const int idx = (blockIdx.x * 256 + threadIdx.x) * 4;
  const int col = idx - (idx / F) * F;
  float4 s = *(const float4*)(P + idx);
  const float4 s1 = *(const float4*)(P + pstride + idx);
  const float4 s2 = *(const float4*)(P + 2 * (size_t)pstride + idx);
  const float4 s3 = *(const float4*)(P + 3 * (size_t)pstride + idx);
  const float4 bv = *(const float4*)(bias + col);
  s.x = fmaxf(s.x + s1.x + s2.x + s3.x + bv.x, 0.0f);
  s.y = fmaxf(s.y + s1.y + s2.y + s3.y + bv.y, 0.0f);
  s.z = fmaxf(s.z + s1.z + s2.z + s3.z + bv.z, 0.0f);
  s.w = fmaxf(s.w + s1.w + s2.w + s3.w + bv.w, 0.0f);
  s16x4 o;
  o[0] = (short)f2bf(s.x); o[1] = (short)f2bf(s.y);
  o[2] = (short)f2bf(s.z); o[3] = (short)f2bf(s.w);
  *(s16x4*)(hb + idx) = o;
}

// ---------------- launch ----------------
extern "C" void kernel_launch(void* const* d_in, const int* in_sizes, int n_in,
                              void* d_out, int out_size, void* d_ws, size_t ws_size,
                              hipStream_t stream) {
  const float* x = (const float*)d_in[0];
  const int* ei = (const int*)d_in[1];
  const int* et = (const int*)d_in[2];
  const float* q = (const float*)d_in[3];
  const float* Wrel1 = (const float*)d_in[4];
  const float* Wroot1 = (const float*)d_in[5];
  const float* b1 = (const float*)d_in[6];
  const float* Wrel2 = (const float*)d_in[7];
  const float* Wroot2 = (const float*)d_in[8];
  const float* b2 = (const float*)d_in[9];
  const float* Wg = (const float*)d_in[10];
  const float* bg = (const float*)d_in[11];
  const float* Wq = (const float*)d_in[12];
  const float* bq = (const float*)d_in[13];

  const int BNn = in_sizes[0] / F;       // 2048
  const int E = in_sizes[1] / 2;         // 65536
  const int L = 64;
  const int Bq = in_sizes[3] / (L * F);  // 8
  const int ML = Bq * L;                 // 512
  const int PSTR = BNn * F;              // partial stride (elements)
  float* out = (float*)d_out;

  char* p = (char*)d_ws;
  auto alloc = [&](size_t bytes) {
    void* r = (void*)p;
    p += (bytes + 255) & ~(size_t)255;
    return r;
  };
  int* cntcur = (int*)alloc((size_t)2 * BNn * 4);  // cnt | cur, one memset
  int* cnt = cntcur;
  int* cur = cntcur + BNn;
  int* offs = (int*)alloc((size_t)(BNn + 1) * 4);
  int* sorted = (int*)alloc((size_t)E * 4);
  unsigned short* Acat = (unsigned short*)alloc((size_t)BNn * 3072 * 2);
  unsigned short* Wcat1 = (unsigned short*)alloc((size_t)F * 3072 * 2);
  unsigned short* Wcat2 = (unsigned short*)alloc((size_t)F * 3072 * 2);
  unsigned short* Wgq = (unsigned short*)alloc((size_t)1536 * F * 2);
  unsigned short* WgR = (unsigned short*)alloc((size_t)F * F * 2);
  unsigned short* WqR = (unsigned short*)alloc((size_t)F * F * 2);
  unsigned short* qbf = (unsigned short*)alloc((size_t)ML * F * 2);
  float* qg = (float*)alloc((size_t)ML * F * 4);
  unsigned short* hb = (unsigned short*)alloc((size_t)BNn * F * 2);
  float* hgz = (float*)alloc((size_t)BNn * 1536 * 4);   // [tq | zh]
  unsigned short* qib = (unsigned short*)alloc((size_t)BNn * F * 2);
  float* parts = (float*)alloc((size_t)4 * PSTR * 4);

  hipMemsetAsync(cntcur, 0, (size_t)2 * BNn * 4, stream);
  khist<<<(E + 255) / 256, 256, 0, stream>>>(ei, E, cnt);
  kscan<<<1, 256, 0, stream>>>(cnt, offs, BNn);
  kscatter<<<(E + 255) / 256, 256, 0, stream>>>(ei, et, E, offs, cur, sorted);

  kcvt<<<BNn + ML, 192, 0, stream>>>(x, q, BNn, Acat, qbf);
  kcvtw<<<3072, 192, 0, stream>>>(Wg, Wq, Wgq, WgR, WqR);
  ktrans<<<dim3(12, 12, 8), 256, 0, stream>>>(Wroot1, Wrel1, Wroot2, Wrel2, Wcat1, Wcat2);

  // qg' = -(q @ Wg[:,F:].T + bg) * log2e  (once, reused by both gates)
  kmm<6><<<dim3(ML / 64, F / 64), 512, 0, stream>>>(
      qbf, F, WgR, F, qg, F, F, bg, nullptr, nullptr, nullptr, 0, NEG_LOG2E, L);

  for (int layer = 0; layer < 2; ++layer) {
    const unsigned short* Wcat = layer ? Wcat2 : Wcat1;
    const float* bb = layer ? b2 : b1;

    // Acat right = per-relation means of Acat left
    kagg<<<BNn, 192, 0, stream>>>(offs, sorted, Acat, Acat + F);

    // parts[s] = Acat[:, s*768:(s+1)*768] @ Wcat[:, s*768:(s+1)*768].T  (split-K x4)
    kmm_pk<<<dim3(BNn / 64, F / 64, 4), 512, 0, stream>>>(
        Acat, 3072, Wcat, 3072, parts, F, PSTR);

    // hb = bf16(relu(sum parts + bias))
    kep_relu<<<(BNn * F) / 1024, 256, 0, stream>>>(parts, PSTR, bb, hb);

    // [hg | zh] = hb @ [WgL | WqL].T with FUSED qi/tanh epilogue on the hg half
    kmm<7><<<dim3(BNn / 64, 1536 / 64), 512, 0, stream>>>(
        hb, F, Wgq, F, hgz, 1536, F, qg, q, nullptr, qib, F, 0.f, L);

    // z = zh + qi @ WqR.T + bq ; out = sig(z)*tq + (1-sig(z))*hb
    if (layer == 0) {
      kmm<3><<<dim3(BNn / 64, F / 64), 512, 0, stream>>>(
          qib, F, WqR, F, nullptr, 0, F, bq, hgz, hb, Acat, 3072, 0.f, L);
    } else {
      kmm<4><<<dim3(BNn / 64, F / 64), 512, 0, stream>>>(
          qib, F, WqR, F, out, F, F, bq, hgz, hb, nullptr, 0, 0.f, L);
    }
  }
}

// Round 8
// 291.223 us; speedup vs baseline: 3.6134x; 1.0920x over previous
//
#include <hip/hip_runtime.h>
#include <hip/hip_bf16.h>
#include <cstdint>
#include <cstddef>

#define F 768

typedef float f32x4 __attribute__((ext_vector_type(4)));
typedef short s16x8 __attribute__((ext_vector_type(8)));
typedef short s16x4 __attribute__((ext_vector_type(4)));

#define NEG_LOG2E (-1.4426950408889634f)

__device__ __forceinline__ float bf2f(unsigned short u) {
  union { unsigned int i; float f; } v; v.i = ((unsigned int)u) << 16; return v.f;
}
__device__ __forceinline__ unsigned short f2bf(float f) {
  union { float f; unsigned int i; } v; v.f = f;
  unsigned int r = v.i + 0x7FFF + ((v.i >> 16) & 1);  // RNE
  return (unsigned short)(r >> 16);
}

#if __has_builtin(__builtin_amdgcn_exp2f)
__device__ __forceinline__ float fexp2(float x) { return __builtin_amdgcn_exp2f(x); }
#else
__device__ __forceinline__ float fexp2(float x) { return exp2f(x); }
#endif
#if __has_builtin(__builtin_amdgcn_rcpf)
__device__ __forceinline__ float frcp(float x) { return __builtin_amdgcn_rcpf(x); }
#else
__device__ __forceinline__ float frcp(float x) { return 1.0f / x; }
#endif

__device__ __forceinline__ float ftanh(float x) {
  float t = fexp2(x * 2.8853900817779268f);
  float s = frcp(t + 1.0f);
  return fmaf(-2.0f, s, 1.0f);
}
__device__ __forceinline__ float fclamp60(float x) {
  return fminf(fmaxf(x, -60.0f), 60.0f);
}

__device__ __forceinline__ void gload16(const void* g, void* l) {
  __builtin_amdgcn_global_load_lds(
      (const __attribute__((address_space(1))) void*)g,
      (__attribute__((address_space(3))) void*)l, 16, 0, 0);
}

// ---------------- CSR build ----------------
__global__ void khist(const int* __restrict__ ei, int E, int* __restrict__ cnt) {
  int e = blockIdx.x * blockDim.x + threadIdx.x;
  if (e < E) atomicAdd(&cnt[ei[E + e]], 1);
}

__global__ void kscan(const int* __restrict__ cnt, int* __restrict__ offs, int n) {
  __shared__ int part[256];
  int t = threadIdx.x;
  const int per = n / 256;  // 8
  int local[8];
  int s = 0;
  for (int j = 0; j < per; ++j) { local[j] = cnt[t * per + j]; s += local[j]; }
  part[t] = s;
  __syncthreads();
  for (int d = 1; d < 256; d <<= 1) {
    int v = (t >= d) ? part[t - d] : 0;
    __syncthreads();
    part[t] += v;
    __syncthreads();
  }
  int run = (t == 0) ? 0 : part[t - 1];
  for (int j = 0; j < per; ++j) { offs[t * per + j] = run; run += local[j]; }
  if (t == 255) offs[n] = run;
}

__global__ void kscatter(const int* __restrict__ ei, const int* __restrict__ et, int E,
                         const int* __restrict__ offs, int* __restrict__ cur,
                         int* __restrict__ sorted) {
  int e = blockIdx.x * blockDim.x + threadIdx.x;
  if (e >= E) return;
  int dst = ei[E + e];
  int pos = offs[dst] + atomicAdd(&cur[dst], 1);
  sorted[pos] = ei[e] | (et[e] << 16);
}

// ---------------- merged prep: x->Acat, q->qbf, Wg/Wq -> Wgq/WgR/WqR ----------------
__global__ void kprep(const float* __restrict__ x, const float* __restrict__ q,
                      const float* __restrict__ Wg, const float* __restrict__ Wq,
                      int nx, int nq,
                      unsigned short* __restrict__ Acat, unsigned short* __restrict__ qbf,
                      unsigned short* __restrict__ Wgq, unsigned short* __restrict__ WgR,
                      unsigned short* __restrict__ WqR) {
  const int b = blockIdx.x, c = threadIdx.x * 4;
  const float* srow;
  unsigned short* drow;
  if (b < nx) {
    srow = x + (size_t)b * F; drow = Acat + (size_t)b * 3072;
  } else if (b < nx + nq) {
    srow = q + (size_t)(b - nx) * F; drow = qbf + (size_t)(b - nx) * F;
  } else {
    const int w = b - nx - nq;  // 0..3071
    if (w < 1536) {
      srow = (w < 768) ? Wg + (size_t)w * 1536 : Wq + (size_t)(w - 768) * 1536;
      drow = Wgq + (size_t)w * 768;
    } else if (w < 2304) {
      srow = Wg + (size_t)(w - 1536) * 1536 + 768;
      drow = WgR + (size_t)(w - 1536) * 768;
    } else {
      srow = Wq + (size_t)(w - 2304) * 1536 + 768;
      drow = WqR + (size_t)(w - 2304) * 768;
    }
  }
  float4 v = *(const float4*)(srow + c);
  s16x4 o;
  o[0] = (short)f2bf(v.x); o[1] = (short)f2bf(v.y);
  o[2] = (short)f2bf(v.z); o[3] = (short)f2bf(v.w);
  *(s16x4*)(drow + c) = o;
}

// transpose-convert: Wcat_l[n][part*768 + k] = Wpart[k][n], grid (12,12,8)
__global__ void ktrans(const float* __restrict__ Wr1, const float* __restrict__ Wl1,
                       const float* __restrict__ Wr2, const float* __restrict__ Wl2,
                       unsigned short* __restrict__ Wcat1, unsigned short* __restrict__ Wcat2) {
  __shared__ float tile[64][65];
  const int z = blockIdx.z, layer = z >> 2, part = z & 3;
  const float* src = (part == 0) ? (layer ? Wr2 : Wr1)
                                 : ((layer ? Wl2 : Wl1) + (size_t)(part - 1) * F * F);
  unsigned short* dst = (layer ? Wcat2 : Wcat1) + part * F;
  const int kt = blockIdx.x * 64, nt = blockIdx.y * 64;
  const int t = threadIdx.x, c = t & 63, r4 = t >> 6;
#pragma unroll
  for (int it = 0; it < 16; ++it) {
    int kk = r4 + it * 4;
    tile[kk][c] = src[(size_t)(kt + kk) * F + nt + c];
  }
  __syncthreads();
#pragma unroll
  for (int it = 0; it < 16; ++it) {
    int rr = r4 + it * 4;
    dst[(size_t)(nt + rr) * 3072 + kt + c] = f2bf(tile[c][rr]);
  }
}

// ---------------- per-(dst,relation) mean; 192 thr, ushort4/lane, unroll 4 ----------
__global__ void kagg(const int* __restrict__ offs, const int* __restrict__ sorted,
                     const unsigned short* __restrict__ hin,   // Acat left, ld 3072
                     unsigned short* __restrict__ dst) {       // Acat + 768
  const int i = blockIdx.x, t = threadIdx.x;
  const int col = t * 4;
  float a0[4] = {}, a1[4] = {}, a2[4] = {};
  int c0 = 0, c1 = 0, c2 = 0;
  const int beg = offs[i], end = offs[i + 1];
  int e = beg;
  for (; e + 3 < end; e += 4) {
    int pk[4];
#pragma unroll
    for (int u = 0; u < 4; ++u) pk[u] = sorted[e + u];
    s16x4 w[4];
#pragma unroll
    for (int u = 0; u < 4; ++u)
      w[u] = *(const s16x4*)(hin + (size_t)(pk[u] & 0xFFFF) * 3072 + col);
#pragma unroll
    for (int u = 0; u < 4; ++u) {
      int r = pk[u] >> 16;
      float v[4];
#pragma unroll
      for (int j = 0; j < 4; ++j) v[j] = bf2f((unsigned short)w[u][j]);
      if (r == 0)      { c0++; for (int j = 0; j < 4; ++j) a0[j] += v[j]; }
      else if (r == 1) { c1++; for (int j = 0; j < 4; ++j) a1[j] += v[j]; }
      else             { c2++; for (int j = 0; j < 4; ++j) a2[j] += v[j]; }
    }
  }
  for (; e < end; ++e) {
    int p0 = sorted[e];
    s16x4 w0 = *(const s16x4*)(hin + (size_t)(p0 & 0xFFFF) * 3072 + col);
    int r0 = p0 >> 16;
    float v0[4];
#pragma unroll
    for (int j = 0; j < 4; ++j) v0[j] = bf2f((unsigned short)w0[j]);
    if (r0 == 0)      { c0++; for (int j = 0; j < 4; ++j) a0[j] += v0[j]; }
    else if (r0 == 1) { c1++; for (int j = 0; j < 4; ++j) a1[j] += v0[j]; }
    else              { c2++; for (int j = 0; j < 4; ++j) a2[j] += v0[j]; }
  }
  const float i0 = frcp((float)(c0 > 0 ? c0 : 1));
  const float i1 = frcp((float)(c1 > 0 ? c1 : 1));
  const float i2 = frcp((float)(c2 > 0 ? c2 : 1));
  unsigned short* d = dst + (size_t)i * 3072 + col;
  s16x4 o;
#pragma unroll
  for (int j = 0; j < 4; ++j) o[j] = (short)f2bf(a0[j] * i0);
  *(s16x4*)d = o;
#pragma unroll
  for (int j = 0; j < 4; ++j) o[j] = (short)f2bf(a1[j] * i1);
  *(s16x4*)(d + F) = o;
#pragma unroll
  for (int j = 0; j < 4; ++j) o[j] = (short)f2bf(a2[j] * i2);
  *(s16x4*)(d + 2 * F) = o;
}

// ---------------- bf16 MFMA GEMM, 64x64 tile, BK=64, 512 thr / 8 waves ----------
// EPI: 3 gate-mix -> bf16 C2 (Acat) | 4 gate-mix -> f32 C (out)
//      6 qgE = exp2(clamp((v+bias)*-log2e)) -> f32 C
//      7 [hg|zh]: bn<768 -> fused qi (1-trans sigmoid via precomputed qgE),
//                 writes qib bf16 + tqb bf16; bn>=768 -> zh f32 -> C(zhb)
template <int EPI>
__launch_bounds__(512)
__global__ void kmm(const unsigned short* __restrict__ A, int lda,
                    const unsigned short* __restrict__ B, int ldb,
                    float* __restrict__ C, int ldc, int K,
                    const float* __restrict__ bias,          // EPI3/4: bq | EPI6: bg | EPI7: qgE
                    const float* __restrict__ auxf,          // EPI3/4: zhb | EPI7: raw q
                    const unsigned short* __restrict__ hbb,  // EPI3/4: hb bf16
                    unsigned short* __restrict__ C2, int ldc2,
                    unsigned short* __restrict__ tqb,        // EPI7: write | EPI3/4: read
                    int Lq) {
  __shared__ unsigned short Asb[2][64 * 64];
  __shared__ unsigned short Bsb[2][64 * 64];
  const int t = threadIdx.x;
  const int lane = t & 63, wid = t >> 6;     // 8 waves
  const int wr = wid >> 2, wc = wid & 3;     // 2 x 4
  const int bm = blockIdx.x * 64, bn = blockIdx.y * 64;

  const int srow = t >> 3, schunk = t & 7;
  const int kxor = ((schunk ^ (srow & 7)) << 3);
  const unsigned short* Ap = A + (size_t)(bm + srow) * lda + kxor;
  const unsigned short* Bp = B + (size_t)(bn + srow) * ldb + kxor;

  const int rA0 = wr * 32 + (lane & 15);
  const int rB0 = wc * 16 + (lane & 15);
  const int l7 = lane & 7, lq = lane >> 4;
  const int s8_0 = (((0 * 4 + lq) ^ l7) << 3);
  const int s8_1 = (((1 * 4 + lq) ^ l7) << 3);

  f32x4 acc[2] = {};

  auto stage = [&](int cb, int k0) {
    gload16(Ap + k0, &Asb[cb][t * 8]);
    gload16(Bp + k0, &Bsb[cb][t * 8]);
  };

  stage(0, 0);
  __syncthreads();
  int cur = 0;
  for (int k0 = 0; k0 < K; k0 += 64) {
    if (k0 + 64 < K) stage(cur ^ 1, k0 + 64);
    const unsigned short* As = Asb[cur];
    const unsigned short* Bs = Bsb[cur];
#pragma unroll
    for (int ks = 0; ks < 2; ++ks) {
      const int s8 = ks ? s8_1 : s8_0;
      s16x8 af[2], bf;
#pragma unroll
      for (int i = 0; i < 2; ++i)
        af[i] = *(const s16x8*)(As + (rA0 + i * 16) * 64 + s8);
      bf = *(const s16x8*)(Bs + rB0 * 64 + s8);
#pragma unroll
      for (int i = 0; i < 2; ++i)
        acc[i] = __builtin_amdgcn_mfma_f32_16x16x32_bf16(af[i], bf, acc[i], 0, 0, 0);
    }
    __syncthreads();
    cur ^= 1;
  }

  const int colw = bn + wc * 16 + (lane & 15);

  if (EPI == 7) {
    if (bn < 768) {
      // sig = 1/(1 + exp2(hg')·qgE_l): 1 trans per (element,l)
      float ea[2][4], qacc[2][4];
#pragma unroll
      for (int i = 0; i < 2; ++i)
#pragma unroll
        for (int j = 0; j < 4; ++j) {
          ea[i][j] = fexp2(fclamp60(acc[i][j] * NEG_LOG2E));
          qacc[i][j] = 0.0f;
        }
      const int b = bm >> 8;
      const float* qb = auxf + (size_t)b * Lq * F;   // raw q
      const float* qeb = bias + (size_t)b * Lq * F;  // qgE
#pragma unroll 4
      for (int l = 0; l < Lq; ++l) {
        const float qe = qeb[(size_t)l * F + colw];
        const float q0 = qb[(size_t)l * F + colw];
#pragma unroll
        for (int i = 0; i < 2; ++i)
#pragma unroll
          for (int j = 0; j < 4; ++j)
            qacc[i][j] = fmaf(frcp(fmaf(ea[i][j], qe, 1.0f)), q0, qacc[i][j]);
      }
#pragma unroll
      for (int i = 0; i < 2; ++i)
#pragma unroll
        for (int j = 0; j < 4; ++j) {
          const int row = bm + wr * 32 + i * 16 + (lane >> 4) * 4 + j;
          C2[(size_t)row * 768 + colw] = f2bf(qacc[i][j]);           // qib
          tqb[(size_t)row * 768 + colw] = f2bf(ftanh(qacc[i][j]));   // tq bf16
        }
    } else {
#pragma unroll
      for (int i = 0; i < 2; ++i)
#pragma unroll
        for (int j = 0; j < 4; ++j) {
          const int row = bm + wr * 32 + i * 16 + (lane >> 4) * 4 + j;
          C[(size_t)row * 768 + (colw - 768)] = acc[i][j];           // zhb
        }
    }
    return;
  }

#pragma unroll
  for (int i = 0; i < 2; ++i)
#pragma unroll
    for (int j = 0; j < 4; ++j) {
      const int row = bm + wr * 32 + i * 16 + (lane >> 4) * 4 + j;
      const int col = colw;
      float v = acc[i][j];
      if (EPI == 3 || EPI == 4) {
        float zh = auxf[(size_t)row * 768 + col];
        float z = v + bias[col] + zh;
        float al = frcp(1.0f + fexp2(z * NEG_LOG2E));
        float tq = bf2f(tqb[(size_t)row * 768 + col]);
        float hv = bf2f(hbb[(size_t)row * 768 + col]);
        float o = al * tq + (1.0f - al) * hv;
        if (EPI == 3) C2[(size_t)row * ldc2 + col] = f2bf(o);
        else          C[(size_t)row * ldc + col] = o;
      } else if (EPI == 6) {
        C[(size_t)row * ldc + col] = fexp2(fclamp60((v + bias[col]) * NEG_LOG2E));
      }
    }
}

// split-K GEMM -> f32 partials. grid (M/64, N/64, 2), 512 thr / 8 waves
__launch_bounds__(512)
__global__ void kmm_pk(const unsigned short* __restrict__ A, int lda,
                       const unsigned short* __restrict__ B, int ldb,
                       float* __restrict__ P, int Ksplit, int pstride) {
  __shared__ unsigned short Asb[2][64 * 64];
  __shared__ unsigned short Bsb[2][64 * 64];
  const int t = threadIdx.x;
  const int lane = t & 63, wid = t >> 6;
  const int wr = wid >> 2, wc = wid & 3;
  const int bm = blockIdx.x * 64, bn = blockIdx.y * 64;
  const int kbase = blockIdx.z * Ksplit;
  float* Cp = P + (size_t)blockIdx.z * pstride;

  const int srow = t >> 3, schunk = t & 7;
  const int kxor = ((schunk ^ (srow & 7)) << 3);
  const unsigned short* Ap = A + (size_t)(bm + srow) * lda + kxor + kbase;
  const unsigned short* Bp = B + (size_t)(bn + srow) * ldb + kxor + kbase;

  const int rA0 = wr * 32 + (lane & 15);
  const int rB0 = wc * 16 + (lane & 15);
  const int l7 = lane & 7, lq = lane >> 4;
  const int s8_0 = (((0 * 4 + lq) ^ l7) << 3);
  const int s8_1 = (((1 * 4 + lq) ^ l7) << 3);

  f32x4 acc[2] = {};

  auto stage = [&](int cb, int k0) {
    gload16(Ap + k0, &Asb[cb][t * 8]);
    gload16(Bp + k0, &Bsb[cb][t * 8]);
  };

  stage(0, 0);
  __syncthreads();
  int cur = 0;
  for (int k0 = 0; k0 < Ksplit; k0 += 64) {
    if (k0 + 64 < Ksplit) stage(cur ^ 1, k0 + 64);
    const unsigned short* As = Asb[cur];
    const unsigned short* Bs = Bsb[cur];
#pragma unroll
    for (int ks = 0; ks < 2; ++ks) {
      const int s8 = ks ? s8_1 : s8_0;
      s16x8 af[2], bf;
#pragma unroll
      for (int i = 0; i < 2; ++i)
        af[i] = *(const s16x8*)(As + (rA0 + i * 16) * 64 + s8);
      bf = *(const s16x8*)(Bs + rB0 * 64 + s8);
#pragma unroll
      for (int i = 0; i < 2; ++i)
        acc[i] = __builtin_amdgcn_mfma_f32_16x16x32_bf16(af[i], bf, acc[i], 0, 0, 0);
    }
    __syncthreads();
    cur ^= 1;
  }

  const int col = bn + wc * 16 + (lane & 15);
#pragma unroll
  for (int i = 0; i < 2; ++i)
#pragma unroll
    for (int j = 0; j < 4; ++j) {
      const int row = bm + wr * 32 + i * 16 + (lane >> 4) * 4 + j;
      Cp[(size_t)row * F + col] = acc[i][j];
    }
}

// reduce 2 partials + bias -> relu -> bf16 hb. grid 1536 x 256, float4/thr.
__global__ void kep_relu(const float* __restrict__ P, int pstride,
                         const float* __restrict__ bias,
                         unsigned short* __restrict__ hb) {
  const int idx = (blockIdx.x * 256 + threadIdx.x) * 4;
  const int col = idx - (idx / F) * F;
  float4 s = *(const float4*)(P + idx);
  const float4 s1 = *(const float4*)(P + pstride + idx);
  const float4 bv = *(const float4*)(bias + col);
  s.x = fmaxf(s.x + s1.x + bv.x, 0.0f);
  s.y = fmaxf(s.y + s1.y + bv.y, 0.0f);
  s.z = fmaxf(s.z + s1.z + bv.z, 0.0f);
  s.w = fmaxf(s.w + s1.w + bv.w, 0.0f);
  s16x4 o;
  o[0] = (short)f2bf(s.x); o[1] = (short)f2bf(s.y);
  o[2] = (short)f2bf(s.z); o[3] = (short)f2bf(s.w);
  *(s16x4*)(hb + idx) = o;
}

// ---------------- launch ----------------
extern "C" void kernel_launch(void* const* d_in, const int* in_sizes, int n_in,
                              void* d_out, int out_size, void* d_ws, size_t ws_size,
                              hipStream_t stream) {
  const float* x = (const float*)d_in[0];
  const int* ei = (const int*)d_in[1];
  const int* et = (const int*)d_in[2];
  const float* q = (const float*)d_in[3];
  const float* Wrel1 = (const float*)d_in[4];
  const float* Wroot1 = (const float*)d_in[5];
  const float* b1 = (const float*)d_in[6];
  const float* Wrel2 = (const float*)d_in[7];
  const float* Wroot2 = (const float*)d_in[8];
  const float* b2 = (const float*)d_in[9];
  const float* Wg = (const float*)d_in[10];
  const float* bg = (const float*)d_in[11];
  const float* Wq = (const float*)d_in[12];
  const float* bq = (const float*)d_in[13];

  const int BNn = in_sizes[0] / F;       // 2048
  const int E = in_sizes[1] / 2;         // 65536
  const int L = 64;
  const int Bq = in_sizes[3] / (L * F);  // 8
  const int ML = Bq * L;                 // 512
  const int PSTR = BNn * F;              // partial stride (elements)
  float* out = (float*)d_out;

  char* p = (char*)d_ws;
  auto alloc = [&](size_t bytes) {
    void* r = (void*)p;
    p += (bytes + 255) & ~(size_t)255;
    return r;
  };
  int* cntcur = (int*)alloc((size_t)2 * BNn * 4);  // cnt | cur, one memset
  int* cnt = cntcur;
  int* cur = cntcur + BNn;
  int* offs = (int*)alloc((size_t)(BNn + 1) * 4);
  int* sorted = (int*)alloc((size_t)E * 4);
  unsigned short* Acat = (unsigned short*)alloc((size_t)BNn * 3072 * 2);
  unsigned short* Wcat1 = (unsigned short*)alloc((size_t)F * 3072 * 2);
  unsigned short* Wcat2 = (unsigned short*)alloc((size_t)F * 3072 * 2);
  unsigned short* Wgq = (unsigned short*)alloc((size_t)1536 * F * 2);
  unsigned short* WgR = (unsigned short*)alloc((size_t)F * F * 2);
  unsigned short* WqR = (unsigned short*)alloc((size_t)F * F * 2);
  unsigned short* qbf = (unsigned short*)alloc((size_t)ML * F * 2);
  float* qgE = (float*)alloc((size_t)ML * F * 4);
  unsigned short* hb = (unsigned short*)alloc((size_t)BNn * F * 2);
  float* zhb = (float*)alloc((size_t)BNn * F * 4);
  unsigned short* tqb = (unsigned short*)alloc((size_t)BNn * F * 2);
  unsigned short* qib = (unsigned short*)alloc((size_t)BNn * F * 2);
  float* parts = (float*)alloc((size_t)2 * PSTR * 4);

  hipMemsetAsync(cntcur, 0, (size_t)2 * BNn * 4, stream);
  khist<<<(E + 255) / 256, 256, 0, stream>>>(ei, E, cnt);
  kscan<<<1, 256, 0, stream>>>(cnt, offs, BNn);
  kscatter<<<(E + 255) / 256, 256, 0, stream>>>(ei, et, E, offs, cur, sorted);

  kprep<<<BNn + ML + 3072, 192, 0, stream>>>(x, q, Wg, Wq, BNn, ML,
                                             Acat, qbf, Wgq, WgR, WqR);
  ktrans<<<dim3(12, 12, 8), 256, 0, stream>>>(Wroot1, Wrel1, Wroot2, Wrel2, Wcat1, Wcat2);

  // qgE = exp2(clamp(-(q @ Wg[:,F:].T + bg)·log2e))  (once, reused by both gates)
  kmm<6><<<dim3(ML / 64, F / 64), 512, 0, stream>>>(
      qbf, F, WgR, F, qgE, F, F, bg, nullptr, nullptr, nullptr, 0, nullptr, L);

  for (int layer = 0; layer < 2; ++layer) {
    const unsigned short* Wcat = layer ? Wcat2 : Wcat1;
    const float* bb = layer ? b2 : b1;

    // Acat right = per-relation means of Acat left
    kagg<<<BNn, 192, 0, stream>>>(offs, sorted, Acat, Acat + F);

    // parts[s] = Acat[:, s*1536:...] @ Wcat[:, s*1536:...].T  (split-K x2, 768 blocks)
    kmm_pk<<<dim3(BNn / 64, F / 64, 2), 512, 0, stream>>>(
        Acat, 3072, Wcat, 3072, parts, 1536, PSTR);

    // hb = bf16(relu(sum parts + bias))
    kep_relu<<<(BNn * F) / 1024, 256, 0, stream>>>(parts, PSTR, bb, hb);

    // [hg | zh] = hb @ [WgL | WqL].T ; fused qi (1-trans sigmoid) on hg half
    kmm<7><<<dim3(BNn / 64, 1536 / 64), 512, 0, stream>>>(
        hb, F, Wgq, F, zhb, F, F, qgE, q, nullptr, qib, F, tqb, L);

    // z = zh + qi @ WqR.T + bq ; out = sig(z)*tq + (1-sig(z))*hb
    if (layer == 0) {
      kmm<3><<<dim3(BNn / 64, F / 64), 512, 0, stream>>>(
          qib, F, WqR, F, nullptr, 0, F, bq, zhb, hb, Acat, 3072, tqb, L);
    } else {
      kmm<4><<<dim3(BNn / 64, F / 64), 512, 0, stream>>>(
          qib, F, WqR, F, out, F, F, bq, zhb, hb, nullptr, 0, tqb, L);
    }
  }
}